// Round 14
// baseline (1044.850 us; speedup 1.0000x reference)
//
#include <hip/hip_runtime.h>
#include <math.h>

#define B_N 32768
#define U_N 256
#define H_N 1024
#define LR_C 0.01f
#define EPS_C 1e-3f

typedef unsigned short ushort_t;
typedef unsigned int uint_t;
using frag8 = __attribute__((ext_vector_type(8))) short;   // 8 bf16 = 4 VGPR
using f32x4 = __attribute__((ext_vector_type(4))) float;   // MFMA acc

// Branchless erf, Abramowitz-Stegun 7.1.26: |abs err| <= 1.5e-7.
__device__ __forceinline__ float erf_fast(float y) {
    float ay = fabsf(y);
    float t = __builtin_amdgcn_rcpf(fmaf(0.3275911f, ay, 1.0f));
    float p = fmaf(1.061405429f, t, -1.453152027f);
    p = fmaf(p, t, 1.421413741f);
    p = fmaf(p, t, -0.284496736f);
    p = fmaf(p, t, 0.254829592f);
    p = p * t;
    float e = __expf(-ay * ay);
    float r = fmaf(-p, e, 1.0f);
    return copysignf(r, y);
}
__device__ __forceinline__ float gelu_f(float x) {
    return 0.5f * x * (1.0f + erf_fast(x * 0.7071067811865475f));
}
// Fused gelu+dgelu: shares the poly AND the exp (exp(-ay^2) == exp(-x^2/2)).
__device__ __forceinline__ void gelu_pair(float x, float& g, float& d) {
    float ay = fabsf(x) * 0.7071067811865475f;
    float t = __builtin_amdgcn_rcpf(fmaf(0.3275911f, ay, 1.0f));
    float p = fmaf(1.061405429f, t, -1.453152027f);
    p = fmaf(p, t, 1.421413741f);
    p = fmaf(p, t, -0.284496736f);
    p = fmaf(p, t, 0.254829592f);
    p = p * t;
    float e = __expf(-ay * ay);
    float er = copysignf(fmaf(-p, e, 1.0f), x);
    float c = 0.5f * (1.0f + er);
    g = x * c;
    d = fmaf(x * 0.3989422804014327f, e, c);
}
__device__ __forceinline__ void splitf(float v, ushort_t& h, ushort_t& l) {
    uint_t u = __float_as_uint(v);
    h = (ushort_t)(u >> 16);
    float r = v - __uint_as_float(u & 0xFFFF0000u);
    uint_t ru = __float_as_uint(r);
    l = (ushort_t)((ru + 0x7FFFu + ((ru >> 16) & 1u)) >> 16);
}
__device__ __forceinline__ ushort_t cvt_rne(float v) {
    uint_t u = __float_as_uint(v);
    return (ushort_t)((u + 0x7FFFu + ((u >> 16) & 1u)) >> 16);
}
__device__ __forceinline__ float bf2f(ushort_t u) {
    return __uint_as_float((uint_t)u << 16);
}
// pa = packed (h<<16)|l for k=2i, pb for k=2i+1 -> hw/lw = bf16x2 hi/lo words
__device__ __forceinline__ void unpack2(uint_t pa, uint_t pb, uint_t& hw, uint_t& lw) {
    hw = __builtin_amdgcn_perm(pb, pa, 0x07060302u);  // [pa.h, pb.h]
    lw = __builtin_amdgcn_perm(pb, pa, 0x05040100u);  // [pa.l, pb.l]
}
// Weight-plane chunk swizzle: element (n,k) of a [N,K] k-major plane lives at
// n*K + (k&~31) | ((((k>>3)&3) ^ ((n>>1)&3))<<3) | (k&7).  16B chunks XOR'd
// within each 64B (32-elem) row-tile so a LINEAR global_load_lds copy yields
// bank-conflict-free ds_read_b128 fragment reads (2 lanes/bank-group = free).
__device__ __forceinline__ size_t swz(int n, int k, int K) {
    return (size_t)n * K +
           (size_t)((k & ~31) | ((((k >> 3) & 3) ^ ((n >> 1) & 3)) << 3) | (k & 7));
}
// 16B global -> LDS DMA (dest = wave-uniform base + lane*16)
__device__ __forceinline__ void gload16(const ushort_t* g, ushort_t* l) {
    __builtin_amdgcn_global_load_lds(
        (const __attribute__((address_space(1))) void*)g,
        (__attribute__((address_space(3))) void*)l, 16, 0, 0);
}

#define EPI_NONE 0
#define EPI_GELU 1
#define EPI_ADDS 3

// bgemm epilogue modes
#define BEP_P   0   // bf16 row-major out
#define BEP_PT  1   // bf16 row-major + col-major [N,M]
#define BEP_A1  2   // g1=gelu rm + gp=dgelu rm + g1T ct
#define BEP_DAT 3   // acc * gp(bf16) -> col-major only

// ---------------------------------------------------------------------------
// 3-pass split-bf16 GEMM (fp32-class). Phase C only.
// B planes (swizzled weights) staged via global_load_lds into unpadded LDS;
// A staged through registers into padded LDS (unpack / split on the fly).
// ---------------------------------------------------------------------------
template<int ACONCAT, int APACK, int EPI, int OPACK>
__global__ __launch_bounds__(256)
void mgemm_k(const float* A, const float* A2, const uint_t* __restrict__ AP,
             const ushort_t* __restrict__ BTh, const ushort_t* __restrict__ BTl,
             const float* __restrict__ bias, const ushort_t* __restrict__ Xr,
             float* C, uint_t* Cp,
             int M, int N, int K)
{
    __shared__ ushort_t Ah[128 * 40], Al[128 * 40];
    __shared__ ushort_t Bh[128 * 32], Bl[128 * 32];
    const int tid = threadIdx.x;
    const int m0 = blockIdx.x * 128, n0 = blockIdx.y * 128;
    const int lane = tid & 63, w = tid >> 6;
    const int wm = (w & 1) * 64, wn = (w >> 1) * 64;
    const int fr = lane & 15, fq = lane >> 4;
    const int sr = tid >> 1;
    const int sk = (tid & 1) * 16;

    f32x4 acc[4][4];
    #pragma unroll
    for (int i = 0; i < 4; i++)
        #pragma unroll
        for (int j = 0; j < 4; j++) acc[i][j] = (f32x4){0.f, 0.f, 0.f, 0.f};

    for (int k0 = 0; k0 < K; k0 += 32) {
        // ---- B: async DMA, linear LDS (source pre-swizzled) ----
        {
            const int r0w = w * 32;
            const size_t so = (size_t)(n0 + r0w + (lane >> 2)) * K + k0 + ((lane & 3) << 3);
            gload16(&BTh[so],                  &Bh[r0w * 32]);
            gload16(&BTh[so + (size_t)16 * K], &Bh[(r0w + 16) * 32]);
            gload16(&BTl[so],                  &Bl[r0w * 32]);
            gload16(&BTl[so + (size_t)16 * K], &Bl[(r0w + 16) * 32]);
        }
        // ---- A: register staging ----
        if (APACK) {
            const uint_t* ap = AP + (size_t)(m0 + sr) * K + k0 + sk;
            uint4 p0 = *(const uint4*)(ap);
            uint4 p1 = *(const uint4*)(ap + 4);
            uint4 p2 = *(const uint4*)(ap + 8);
            uint4 p3 = *(const uint4*)(ap + 12);
            uint4 h0, h1, l0, l1;
            unpack2(p0.x, p0.y, h0.x, l0.x); unpack2(p0.z, p0.w, h0.y, l0.y);
            unpack2(p1.x, p1.y, h0.z, l0.z); unpack2(p1.z, p1.w, h0.w, l0.w);
            unpack2(p2.x, p2.y, h1.x, l1.x); unpack2(p2.z, p2.w, h1.y, l1.y);
            unpack2(p3.x, p3.y, h1.z, l1.z); unpack2(p3.z, p3.w, h1.w, l1.w);
            *(uint4*)&Ah[sr * 40 + sk]     = h0;
            *(uint4*)&Ah[sr * 40 + sk + 8] = h1;
            *(uint4*)&Al[sr * 40 + sk]     = l0;
            *(uint4*)&Al[sr * 40 + sk + 8] = l1;
        } else {
            #pragma unroll
            for (int g = 0; g < 2; g++) {
                uint4 qh, qa;
                uint_t ph[4], pl[4];
                #pragma unroll
                for (int c = 0; c < 2; c++) {
                    const int ak = k0 + sk + g * 8 + c * 4;
                    const float* ap;
                    if (ACONCAT) ap = (ak < 256) ? (A + (size_t)(m0 + sr) * 256 + ak)
                                                 : (A2 + (size_t)(m0 + sr) * 256 + (ak - 256));
                    else         ap = A + (size_t)(m0 + sr) * K + ak;
                    float4 v = *(const float4*)ap;
                    ushort_t h0,h1,h2,h3,l0,l1,l2,l3;
                    splitf(v.x,h0,l0); splitf(v.y,h1,l1); splitf(v.z,h2,l2); splitf(v.w,h3,l3);
                    ph[c*2]   = (uint_t)h0 | ((uint_t)h1 << 16);
                    ph[c*2+1] = (uint_t)h2 | ((uint_t)h3 << 16);
                    pl[c*2]   = (uint_t)l0 | ((uint_t)l1 << 16);
                    pl[c*2+1] = (uint_t)l2 | ((uint_t)l3 << 16);
                }
                qh.x = ph[0]; qh.y = ph[1]; qh.z = ph[2]; qh.w = ph[3];
                qa.x = pl[0]; qa.y = pl[1]; qa.z = pl[2]; qa.w = pl[3];
                *(uint4*)&Ah[sr * 40 + sk + g * 8] = qh;
                *(uint4*)&Al[sr * 40 + sk + g * 8] = qa;
            }
        }
        __syncthreads();

        frag8 afh[4], afl[4], bfh[4], bfl[4];
        #pragma unroll
        for (int i = 0; i < 4; i++) {
            const int ar = wm + i * 16 + fr;
            afh[i] = *(frag8*)&Ah[ar * 40 + fq * 8];
            afl[i] = *(frag8*)&Al[ar * 40 + fq * 8];
        }
        #pragma unroll
        for (int j = 0; j < 4; j++) {
            const int br = wn + j * 16 + fr;
            const int bs = br * 32 + ((fq ^ ((br >> 1) & 3)) << 3);
            bfh[j] = *(frag8*)&Bh[bs];
            bfl[j] = *(frag8*)&Bl[bs];
        }
        #pragma unroll
        for (int i = 0; i < 4; i++)
            #pragma unroll
            for (int j = 0; j < 4; j++) {
                acc[i][j] = __builtin_amdgcn_mfma_f32_16x16x32_bf16(afh[i], bfh[j], acc[i][j], 0, 0, 0);
                acc[i][j] = __builtin_amdgcn_mfma_f32_16x16x32_bf16(afh[i], bfl[j], acc[i][j], 0, 0, 0);
                acc[i][j] = __builtin_amdgcn_mfma_f32_16x16x32_bf16(afl[i], bfh[j], acc[i][j], 0, 0, 0);
            }
        __syncthreads();
    }

    float bv[4] = {0.f, 0.f, 0.f, 0.f};
    if (bias != nullptr)
        #pragma unroll
        for (int j = 0; j < 4; j++) bv[j] = bias[n0 + wn + j * 16 + fr];
    #pragma unroll
    for (int i = 0; i < 4; i++)
        #pragma unroll
        for (int j = 0; j < 4; j++) {
            const int col = n0 + wn + j * 16 + fr;
            #pragma unroll
            for (int r = 0; r < 4; r++) {
                const int row = m0 + wm + i * 16 + fq * 4 + r;
                const size_t off = (size_t)row * N + col;
                float c = acc[i][j][r] + bv[j];
                if (EPI == EPI_GELU)      c = gelu_f(c);
                else if (EPI == EPI_ADDS) c = c + 0.1f * bf2f(Xr[off]);
                if (OPACK) {
                    ushort_t h, l;
                    splitf(c, h, l);
                    Cp[off] = ((uint_t)h << 16) | (uint_t)l;
                } else {
                    C[off] = c;
                }
            }
        }
}

// ---------------------------------------------------------------------------
// 1-pass bf16 GEMM (Phase A). B plane (swizzled weights) via global_load_lds;
// A through registers into padded LDS. Optional fused column-sum (dbsum).
// ---------------------------------------------------------------------------
template<int ACONCAT, int BEP>
__global__ __launch_bounds__(256)
void bgemm_k(const void* Av, const float* A2f, const ushort_t* __restrict__ BTh,
             const float* __restrict__ bias, const ushort_t* __restrict__ GpIn,
             ushort_t* Crm, ushort_t* Cct, ushort_t* GpOut, float* dbsum,
             int M, int N, int K)
{
    __shared__ ushort_t Ah[128 * 40];
    __shared__ ushort_t Bh[128 * 32];
    const int tid = threadIdx.x;
    const int m0 = blockIdx.x * 128, n0 = blockIdx.y * 128;
    const int lane = tid & 63, w = tid >> 6;
    const int wm = (w & 1) * 64, wn = (w >> 1) * 64;
    const int fr = lane & 15, fq = lane >> 4;
    const int sr = tid >> 1;
    const int sk = (tid & 1) * 16;

    f32x4 acc[4][4];
    #pragma unroll
    for (int i = 0; i < 4; i++)
        #pragma unroll
        for (int j = 0; j < 4; j++) acc[i][j] = (f32x4){0.f, 0.f, 0.f, 0.f};

    for (int k0 = 0; k0 < K; k0 += 32) {
        // ---- B: async DMA ----
        {
            const int r0w = w * 32;
            const size_t so = (size_t)(n0 + r0w + (lane >> 2)) * K + k0 + ((lane & 3) << 3);
            gload16(&BTh[so],                  &Bh[r0w * 32]);
            gload16(&BTh[so + (size_t)16 * K], &Bh[(r0w + 16) * 32]);
        }
        // ---- A ----
        if (ACONCAT) {
            const float* A = (const float*)Av;
            #pragma unroll
            for (int g = 0; g < 2; g++) {
                uint_t ph[4];
                #pragma unroll
                for (int c = 0; c < 2; c++) {
                    const int ak = k0 + sk + g * 8 + c * 4;
                    const float* ap = (ak < 256) ? (A + (size_t)(m0 + sr) * 256 + ak)
                                                 : (A2f + (size_t)(m0 + sr) * 256 + (ak - 256));
                    float4 v = *(const float4*)ap;
                    ph[c*2]   = (uint_t)cvt_rne(v.x) | ((uint_t)cvt_rne(v.y) << 16);
                    ph[c*2+1] = (uint_t)cvt_rne(v.z) | ((uint_t)cvt_rne(v.w) << 16);
                }
                uint4 q; q.x = ph[0]; q.y = ph[1]; q.z = ph[2]; q.w = ph[3];
                *(uint4*)&Ah[sr * 40 + sk + g * 8] = q;
            }
        } else {
            const ushort_t* A = (const ushort_t*)Av;
            const size_t ao = (size_t)(m0 + sr) * K + k0 + sk;
            *(uint4*)&Ah[sr * 40 + sk]     = *(const uint4*)&A[ao];
            *(uint4*)&Ah[sr * 40 + sk + 8] = *(const uint4*)&A[ao + 8];
        }
        __syncthreads();

        frag8 af[4], bf[4];
        #pragma unroll
        for (int i = 0; i < 4; i++) af[i] = *(frag8*)&Ah[(wm + i * 16 + fr) * 40 + fq * 8];
        #pragma unroll
        for (int j = 0; j < 4; j++) {
            const int br = wn + j * 16 + fr;
            bf[j] = *(frag8*)&Bh[br * 32 + ((fq ^ ((br >> 1) & 3)) << 3)];
        }
        #pragma unroll
        for (int i = 0; i < 4; i++)
            #pragma unroll
            for (int j = 0; j < 4; j++)
                acc[i][j] = __builtin_amdgcn_mfma_f32_16x16x32_bf16(af[i], bf[j], acc[i][j], 0, 0, 0);
        __syncthreads();
    }

    float bv[4] = {0.f, 0.f, 0.f, 0.f};
    if (bias != nullptr)
        #pragma unroll
        for (int j = 0; j < 4; j++) bv[j] = bias[n0 + wn + j * 16 + fr];
    float cs[4] = {0.f, 0.f, 0.f, 0.f};
    #pragma unroll
    for (int i = 0; i < 4; i++)
        #pragma unroll
        for (int j = 0; j < 4; j++) {
            const int col = n0 + wn + j * 16 + fr;
            const int rowb = m0 + wm + i * 16 + fq * 4;
            float v[4];
            #pragma unroll
            for (int r = 0; r < 4; r++) v[r] = acc[i][j][r] + bv[j];
            if (BEP == BEP_A1) {
                ushort_t gc[4];
                #pragma unroll
                for (int r = 0; r < 4; r++) {
                    float g, d;
                    gelu_pair(v[r], g, d);
                    gc[r] = cvt_rne(g);
                    Crm[(size_t)(rowb + r) * N + col] = gc[r];
                    GpOut[(size_t)(rowb + r) * N + col] = cvt_rne(d);
                }
                uint_t p0 = (uint_t)gc[0] | ((uint_t)gc[1] << 16);
                uint_t p1 = (uint_t)gc[2] | ((uint_t)gc[3] << 16);
                *(uint2*)&Cct[(size_t)col * M + rowb] = (uint2){p0, p1};
            } else if (BEP == BEP_DAT) {
                ushort_t dc[4];
                #pragma unroll
                for (int r = 0; r < 4; r++) {
                    float pr = v[r] * bf2f(GpIn[(size_t)(rowb + r) * N + col]);
                    dc[r] = cvt_rne(pr);
                    cs[j] += pr;
                }
                uint_t p0 = (uint_t)dc[0] | ((uint_t)dc[1] << 16);
                uint_t p1 = (uint_t)dc[2] | ((uint_t)dc[3] << 16);
                *(uint2*)&Cct[(size_t)col * M + rowb] = (uint2){p0, p1};
            } else {
                ushort_t cc[4];
                #pragma unroll
                for (int r = 0; r < 4; r++) {
                    cc[r] = cvt_rne(v[r]);
                    Crm[(size_t)(rowb + r) * N + col] = cc[r];
                }
                cs[j] += v[0] + v[1] + v[2] + v[3];
                if (BEP == BEP_PT) {
                    uint_t p0 = (uint_t)cc[0] | ((uint_t)cc[1] << 16);
                    uint_t p1 = (uint_t)cc[2] | ((uint_t)cc[3] << 16);
                    *(uint2*)&Cct[(size_t)col * M + rowb] = (uint2){p0, p1};
                }
            }
        }
    if (dbsum != nullptr) {
        #pragma unroll
        for (int j = 0; j < 4; j++) {
            float s = cs[j];
            s += __shfl_xor(s, 16);
            s += __shfl_xor(s, 32);
            if (fq == 0) atomicAdd(&dbsum[n0 + wn + j * 16 + fr], s);
        }
    }
}

// ---------------------------------------------------------------------------
// Weight-grad: C[M,N] += AT[M,:]·BT[N,:] over split-K chunk. Both k-major bf16.
// ---------------------------------------------------------------------------
__global__ __launch_bounds__(256)
void wgrad_k(const ushort_t* __restrict__ AT, const ushort_t* __restrict__ BTt,
             float* C, int M, int N, int KA, int kofsA, int KB, int kofsB, int KC)
{
    __shared__ ushort_t Ah[128 * 40];
    __shared__ ushort_t Bh[128 * 40];
    const int tid = threadIdx.x;
    const int m0 = blockIdx.x * 128, n0 = blockIdx.y * 128;
    const int kbA = kofsA + blockIdx.z * KC;
    const int kbB = kofsB + blockIdx.z * KC;
    const int lane = tid & 63, w = tid >> 6;
    const int wm = (w & 1) * 64, wn = (w >> 1) * 64;
    const int fr = lane & 15, fq = lane >> 4;
    const int sr = tid >> 1;
    const int sk = (tid & 1) * 16;

    f32x4 acc[4][4];
    #pragma unroll
    for (int i = 0; i < 4; i++)
        #pragma unroll
        for (int j = 0; j < 4; j++) acc[i][j] = (f32x4){0.f, 0.f, 0.f, 0.f};

    for (int k0 = 0; k0 < KC; k0 += 32) {
        const size_t ao = (size_t)(m0 + sr) * KA + kbA + k0 + sk;
        *(uint4*)&Ah[sr * 40 + sk]     = *(const uint4*)&AT[ao];
        *(uint4*)&Ah[sr * 40 + sk + 8] = *(const uint4*)&AT[ao + 8];
        const size_t bo = (size_t)(n0 + sr) * KB + kbB + k0 + sk;
        *(uint4*)&Bh[sr * 40 + sk]     = *(const uint4*)&BTt[bo];
        *(uint4*)&Bh[sr * 40 + sk + 8] = *(const uint4*)&BTt[bo + 8];
        __syncthreads();

        frag8 af[4], bf[4];
        #pragma unroll
        for (int i = 0; i < 4; i++) af[i] = *(frag8*)&Ah[(wm + i * 16 + fr) * 40 + fq * 8];
        #pragma unroll
        for (int j = 0; j < 4; j++) bf[j] = *(frag8*)&Bh[(wn + j * 16 + fr) * 40 + fq * 8];
        #pragma unroll
        for (int i = 0; i < 4; i++)
            #pragma unroll
            for (int j = 0; j < 4; j++)
                acc[i][j] = __builtin_amdgcn_mfma_f32_16x16x32_bf16(af[i], bf[j], acc[i][j], 0, 0, 0);
        __syncthreads();
    }
    #pragma unroll
    for (int i = 0; i < 4; i++)
        #pragma unroll
        for (int j = 0; j < 4; j++) {
            const int col = n0 + wn + j * 16 + fr;
            #pragma unroll
            for (int r = 0; r < 4; r++) {
                const int row = m0 + wm + i * 16 + fq * 4 + r;
                atomicAdd(&C[(size_t)row * N + col], acc[i][j][r]);
            }
        }
}

// LayerNorm fwd + dL/dr0, bf16 in/out (dr0 may alias r0).
// Also emits dr0^T (col-major [256, LD]) via LDS transpose, for the G2 wgrad.
__global__ __launch_bounds__(256)
void ln_bf_k(const ushort_t* r0, const ushort_t* __restrict__ phi,
             const float* __restrict__ gamma, const float* __restrict__ beta,
             ushort_t* recon, ushort_t* dr0, ushort_t* dr0T, int LD)
{
    __shared__ ushort_t tds[4][256];
    const int lane = threadIdx.x & 63;
    const int wv = threadIdx.x >> 6;
    const int row = blockIdx.x * 4 + wv;
    const size_t base = (size_t)row * U_N + (lane << 2);

    uint2 xu = *(const uint2*)(r0 + base);
    uint2 pu = *(const uint2*)(phi + base);
    float xs[4] = { bf2f((ushort_t)(xu.x & 0xFFFF)), bf2f((ushort_t)(xu.x >> 16)),
                    bf2f((ushort_t)(xu.y & 0xFFFF)), bf2f((ushort_t)(xu.y >> 16)) };
    float ps[4] = { bf2f((ushort_t)(pu.x & 0xFFFF)), bf2f((ushort_t)(pu.x >> 16)),
                    bf2f((ushort_t)(pu.y & 0xFFFF)), bf2f((ushort_t)(pu.y >> 16)) };
    float s = xs[0] + xs[1] + xs[2] + xs[3];
    float sq = xs[0]*xs[0] + xs[1]*xs[1] + xs[2]*xs[2] + xs[3]*xs[3];
    #pragma unroll
    for (int o = 32; o > 0; o >>= 1) { s += __shfl_xor(s, o); sq += __shfl_xor(sq, o); }
    const float m   = s * (1.0f / U_N);
    const float var = sq * (1.0f / U_N) - m * m;
    const float inv = rsqrtf(var + EPS_C);

    float4 gv = *(const float4*)(gamma + (lane << 2));
    float4 bvv = *(const float4*)(beta + (lane << 2));
    float gs[4] = {gv.x, gv.y, gv.z, gv.w};
    float bs[4] = {bvv.x, bvv.y, bvv.z, bvv.w};
    float rh[4], dh[4], rc[4];
    float s1 = 0.f, s2 = 0.f;
    const float gscale = 2.0f / ((float)B_N * (float)U_N);
    #pragma unroll
    for (int j = 0; j < 4; j++) {
        rh[j] = (xs[j] - m) * inv;
        rc[j] = rh[j] * gs[j] + bs[j];
        float g2 = gscale * (rc[j] - ps[j]);
        dh[j] = g2 * gs[j];
        s1 += dh[j];
        s2 += dh[j] * rh[j];
    }
    #pragma unroll
    for (int o = 32; o > 0; o >>= 1) { s1 += __shfl_xor(s1, o); s2 += __shfl_xor(s2, o); }
    const float mu1 = s1 * (1.0f / U_N);
    const float mu2 = s2 * (1.0f / U_N);
    ushort_t oc[4], dc[4];
    #pragma unroll
    for (int j = 0; j < 4; j++) {
        oc[j] = cvt_rne(rc[j]);
        dc[j] = cvt_rne(inv * (dh[j] - mu1 - rh[j] * mu2));
    }
    *(uint2*)(recon + base) = (uint2){ (uint_t)oc[0] | ((uint_t)oc[1] << 16),
                                       (uint_t)oc[2] | ((uint_t)oc[3] << 16) };
    uint2 dpk = (uint2){ (uint_t)dc[0] | ((uint_t)dc[1] << 16),
                         (uint_t)dc[2] | ((uint_t)dc[3] << 16) };
    *(uint2*)(dr0 + base) = dpk;
    *(uint2*)&tds[wv][lane << 2] = dpk;
    __syncthreads();
    const int col = threadIdx.x;
    uint_t p0 = (uint_t)tds[0][col] | ((uint_t)tds[1][col] << 16);
    uint_t p1 = (uint_t)tds[2][col] | ((uint_t)tds[3][col] << 16);
    *(uint2*)&dr0T[(size_t)col * LD + blockIdx.x * 4] = (uint2){p0, p1};
}

// column sums of row-major bf16 D [rows, 256] -> cs[256] (atomic +=)
__global__ __launch_bounds__(256)
void colsum_rm_k(const ushort_t* __restrict__ D, float* cs, int rows)
{
    __shared__ float red[4][256];
    const int tid = threadIdx.x;
    const int cg = (tid & 63) << 2;     // col group base
    const int rg = tid >> 6;            // row phase
    float a0 = 0.f, a1 = 0.f, a2 = 0.f, a3 = 0.f;
    const int rpb = rows / gridDim.x;
    const int r0 = blockIdx.x * rpb;
    for (int r = r0 + rg; r < r0 + rpb; r += 4) {
        uint2 q = *(const uint2*)&D[(size_t)r * 256 + cg];
        a0 += bf2f((ushort_t)(q.x & 0xFFFF)); a1 += bf2f((ushort_t)(q.x >> 16));
        a2 += bf2f((ushort_t)(q.y & 0xFFFF)); a3 += bf2f((ushort_t)(q.y >> 16));
    }
    red[rg][cg]     = a0;
    red[rg][cg + 1] = a1;
    red[rg][cg + 2] = a2;
    red[rg][cg + 3] = a3;
    __syncthreads();
    const int c = tid;
    float ssum = red[0][c] + red[1][c] + red[2][c] + red[3][c];
    atomicAdd(&cs[c], ssum);
}

// transpose + split: W [R,C] fp32 -> Th (+Tl if HASL) [C,R], chunk-swizzled
template<int HASL>
__global__ __launch_bounds__(256)
void tsplit_k(const float* __restrict__ W, ushort_t* __restrict__ Th,
              ushort_t* __restrict__ Tl, int R, int C)
{
    __shared__ float t[64][65];
    const int tid = threadIdx.x;
    const int R0 = blockIdx.x * 64, C0 = blockIdx.y * 64;
    const int c = tid & 63, rb = (tid >> 6) * 16;
    for (int i = 0; i < 16; i++)
        t[rb + i][c] = W[(size_t)(R0 + rb + i) * C + C0 + c];
    __syncthreads();
    const int orr = tid & 63, ob = (tid >> 6) * 16;
    for (int i = 0; i < 16; i++) {
        const int oc = ob + i;
        ushort_t h, l;
        splitf(t[orr][oc], h, l);
        const size_t d = swz(C0 + oc, R0 + orr, R);
        Th[d] = h;
        if (HASL) Tl[d] = l;
    }
}

// transpose + SGD update + split (hi+lo), chunk-swizzled
__global__ __launch_bounds__(256)
void tupd_k(const float* __restrict__ W, const float* __restrict__ dW,
            ushort_t* __restrict__ Th, ushort_t* __restrict__ Tl, int R, int C)
{
    __shared__ float t[64][65];
    const int tid = threadIdx.x;
    const int R0 = blockIdx.x * 64, C0 = blockIdx.y * 64;
    const int c = tid & 63, rb = (tid >> 6) * 16;
    for (int i = 0; i < 16; i++) {
        const size_t o = (size_t)(R0 + rb + i) * C + C0 + c;
        t[rb + i][c] = W[o] - LR_C * dW[o];
    }
    __syncthreads();
    const int orr = tid & 63, ob = (tid >> 6) * 16;
    for (int i = 0; i < 16; i++) {
        const int oc = ob + i;
        ushort_t h, l;
        splitf(t[orr][oc], h, l);
        const size_t d = swz(C0 + oc, R0 + orr, R);
        Th[d] = h;
        Tl[d] = l;
    }
}

// elementwise hi-plane convert, chunk-swizzled. Row length fixed at 256.
__global__ __launch_bounds__(256)
void scvt_k(const float* __restrict__ W, ushort_t* __restrict__ Th, int n4)
{
    const int i = blockIdx.x * 256 + threadIdx.x;
    if (i >= n4) return;
    float4 v = *(const float4*)(W + (size_t)i * 4);
    const int f = i * 4;
    const int row = f >> 8, col = f & 255;
    uint2 ph;
    ph.x = (uint_t)cvt_rne(v.x) | ((uint_t)cvt_rne(v.y) << 16);
    ph.y = (uint_t)cvt_rne(v.z) | ((uint_t)cvt_rne(v.w) << 16);
    *(uint2*)&Th[swz(row, col, 256)] = ph;
}

// Wc = W2 @ Wg (fp32): W2 [1024,256], Wg [256,256] -> Wc [1024,256]
__global__ __launch_bounds__(256)
void wcmul_k(const float* __restrict__ W2, const float* __restrict__ Wg,
             float* __restrict__ Wc)
{
    const int i = blockIdx.x;
    const int j = threadIdx.x;
    float s = 0.f;
    for (int k = 0; k < 256; k++)
        s = fmaf(W2[i * 256 + k], Wg[k * 256 + j], s);
    Wc[i * 256 + j] = s;
}
// bc = b2 @ Wg + g_bias
__global__ __launch_bounds__(256)
void bcmul_k(const float* __restrict__ b2, const float* __restrict__ Wg,
             const float* __restrict__ gb, float* __restrict__ bc)
{
    const int j = threadIdx.x;
    float s = gb[j];
    for (int k = 0; k < 256; k++)
        s = fmaf(b2[k], Wg[k * 256 + j], s);
    bc[j] = s;
}
// dW2 = G2 @ Wg^T : G2 [1024,256], Wg [256,256] -> dW2[i,u] = sum_v G2[i,v]*Wg[u,v]
__global__ __launch_bounds__(256)
void dw2f_k(const float* __restrict__ G2, const float* __restrict__ Wg,
            float* __restrict__ dW2)
{
    const int i = blockIdx.x;
    const int u = threadIdx.x;
    float s = 0.f;
    for (int v = 0; v < 256; v++)
        s = fmaf(G2[i * 256 + v], Wg[u * 256 + v], s);
    dW2[i * 256 + u] = s;
}
// db2 = cs2 @ Wg^T : db2[u] = sum_v cs2[v]*Wg[u,v]
__global__ __launch_bounds__(256)
void db2f_k(const float* __restrict__ cs2, const float* __restrict__ Wg,
            float* __restrict__ db2)
{
    const int u = threadIdx.x;
    float s = 0.f;
    for (int v = 0; v < 256; v++)
        s = fmaf(cs2[v], Wg[u * 256 + v], s);
    db2[u] = s;
}

__global__ __launch_bounds__(256)
void bupd_k(const float* __restrict__ b1, const float* __restrict__ db1,
            const float* __restrict__ b2, const float* __restrict__ db2,
            float* __restrict__ b1u, float* __restrict__ b2u)
{
    const int i = blockIdx.x * 256 + threadIdx.x;
    if (i < H_N) b1u[i] = b1[i] - LR_C * db1[i];
    else if (i < H_N + U_N) b2u[i - H_N] = b2[i - H_N] - LR_C * db2[i - H_N];
}

extern "C" void kernel_launch(void* const* d_in, const int* in_sizes, int n_in,
                              void* d_out, int out_size, void* d_ws, size_t ws_size,
                              hipStream_t stream)
{
    const float* x      = (const float*)d_in[0];
    const float* h_prev = (const float*)d_in[1];
    const float* W_phi  = (const float*)d_in[2];
    const float* b_phi  = (const float*)d_in[3];
    const float* W_psi  = (const float*)d_in[4];
    const float* b_psi  = (const float*)d_in[5];
    const float* W1     = (const float*)d_in[6];
    const float* b1     = (const float*)d_in[7];
    const float* W2     = (const float*)d_in[8];
    const float* b2     = (const float*)d_in[9];
    const float* W_g    = (const float*)d_in[10];
    const float* g_bias = (const float*)d_in[11];
    const float* gamma  = (const float*)d_in[12];
    const float* beta   = (const float*)d_in[13];
    const float* W_h    = (const float*)d_in[14];
    const float* h_bias = (const float*)d_in[15];
    float* out = (float*)d_out;

    const size_t BU = (size_t)B_N * U_N;
    const size_t UH = (size_t)U_N * H_N;

    // ---- fixed allocations ----
    float* ws  = (float*)d_ws;
    float* dW1 = ws;                      // [U,H]
    float* db1 = dW1 + UH;                // [H]
    float* G2  = db1 + H_N;               // [H,U]  (g1^T @ dr0 accumulator)
    float* cs2 = G2 + UH;                 // [U]    (colsum of dr0)
    float* b1u = cs2 + U_N;
    float* b2u = b1u + H_N;
    float* bc  = b2u + U_N;               // [U] fused r0 bias
    float* Wc  = bc + U_N;                // [H,U] fp32 = W2@Wg
    float* dW2f= Wc + UH;                 // [H,U] finalized dW2
    float* db2f= dW2f + UH;               // [U]
    ushort_t* us = (ushort_t*)(((uintptr_t)(db2f + U_N) + 15) & ~(uintptr_t)15);
    // weight planes (all chunk-swizzled)
    ushort_t* WphiT_h = us;                   // [U,512]
    ushort_t* WpsiT_h = WphiT_h + 131072;     ushort_t* WpsiT_l = WpsiT_h + 131072;
    ushort_t* WcT_h   = WpsiT_l + 131072;     // [U,H] = (W2@Wg)^T
    ushort_t* W1T_h   = WcT_h + 262144;       // [H,U]
    ushort_t* Wcs_h   = W1T_h + 262144;       // Wc row-major [H,U]
    ushort_t* W1uT_h  = Wcs_h + 262144;       ushort_t* W1uT_l = W1uT_h + 262144;
    ushort_t* W2uT_h  = W1uT_l + 262144;      ushort_t* W2uT_l = W2uT_h + 262144;
    ushort_t* WhT_h   = W2uT_l + 262144;      ushort_t* WhT_l  = WhT_h + 65536;
    // persistent bf16 activations
    ushort_t* phi_bf  = WhT_l + 65536;        // [B,U]
    ushort_t* phiT_bf = phi_bf + BU;          // [U,B]
    ushort_t* recon_bf= phiT_bf + BU;         // [B,U]
    ushort_t* chunk0  = recon_bf + BU;        // chunk region start
    const size_t P_bytes = (size_t)((char*)chunk0 - (char*)d_ws);

    // ---- chunk sizing ----
    int GA = 2;
    while (GA < 256 && P_bytes + (size_t)(B_N / GA) * 10240 + (1 << 20) > ws_size) GA *= 2;
    size_t region = (size_t)(B_N / GA) * 10240;
    int GC = 1;
    while (GC < 256) {
        size_t cC = (size_t)(B_N / GC) * 6144;
        size_t r = cC > region ? cC : region;
        if (P_bytes + r + (1 << 20) <= ws_size) { region = r; break; }
        GC *= 2;
    }
    const int BcA = B_N / GA;
    const int BcC = B_N / GC;
    const int KC = (BcA >= 8192) ? 512 : ((BcA >= 1024) ? BcA / 16 : BcA);
    const int Z  = BcA / KC;

    // Phase A chunk buffers (bf16)
    ushort_t* g1  = chunk0;                       // [BcA,H]
    ushort_t* gp  = g1  + (size_t)BcA * H_N;      // [BcA,H]
    ushort_t* g1T = gp  + (size_t)BcA * H_N;      // [H,BcA]
    ushort_t* daT = g1T + (size_t)BcA * H_N;      // [H,BcA]
    ushort_t* e_b = daT + (size_t)BcA * H_N;      // [BcA,U]  (unused; layout kept)
    ushort_t* r0b = e_b + (size_t)BcA * U_N;      // [BcA,U]  (r0 -> dr0)
    ushort_t* deb = r0b + (size_t)BcA * U_N;      // [BcA,U]  (unused)
    ushort_t* drT = deb + (size_t)BcA * U_N;      // [U,BcA]  dr0^T
    // Phase C chunk buffers (packed hi|lo words, overlay same region)
    uint_t* psi_p  = (uint_t*)chunk0;             // [BcC,U]
    uint_t* h2_p   = psi_p + (size_t)BcC * U_N;   // [BcC,H]
    uint_t* feat_p = h2_p  + (size_t)BcC * H_N;   // [BcC,U]

    // zero: dW1 [UH], db1 [H], G2 [UH], cs2 [U] (contiguous)
    hipMemsetAsync(dW1, 0, (2 * UH + H_N + U_N) * sizeof(float), stream);

    dim3 blk(256);
    // weight prep (planes stored chunk-swizzled)
    tsplit_k<0><<<dim3(8, 4),  blk, 0, stream>>>(W_phi, WphiT_h, nullptr, 512, 256);
    tsplit_k<1><<<dim3(8, 4),  blk, 0, stream>>>(W_psi, WpsiT_h, WpsiT_l, 512, 256);
    tsplit_k<0><<<dim3(4, 16), blk, 0, stream>>>(W1, W1T_h, nullptr, 256, 1024);
    tsplit_k<1><<<dim3(4, 4),  blk, 0, stream>>>(W_h, WhT_h, WhT_l, 256, 256);
    // Wc = W2@Wg, bc = b2@Wg + g_bias (folds the e-GEMM and de-GEMM away)
    wcmul_k<<<dim3(1024), blk, 0, stream>>>(W2, W_g, Wc);
    bcmul_k<<<dim3(1), blk, 0, stream>>>(b2, W_g, g_bias, bc);
    tsplit_k<0><<<dim3(16, 4), blk, 0, stream>>>(Wc, WcT_h, nullptr, 1024, 256);
    scvt_k<<<dim3(256), blk, 0, stream>>>(Wc, Wcs_h, 65536);

    // phi = [x|h_prev] @ W_phi + b_phi  (1-pass, bf16 out rm + T)
    bgemm_k<1, BEP_PT><<<dim3(B_N / 128, 2), blk, 0, stream>>>(
        x, h_prev, WphiT_h, b_phi, nullptr, phi_bf, phiT_bf, nullptr, nullptr,
        B_N, U_N, 512);

    // ---- Phase A: inner fwd+bwd, 1-pass bf16, chunked ----
    for (int c = 0; c < GA; c++) {
        const size_t off = (size_t)c * BcA;
        const ushort_t* phic = phi_bf + off * U_N;
        // a1 = phi@W1+b1 -> g1(gelu) rm, gp(dgelu) rm, g1T ct
        bgemm_k<0, BEP_A1><<<dim3(BcA / 128, 8), blk, 0, stream>>>(
            phic, nullptr, W1T_h, b1, nullptr, g1, g1T, gp, nullptr, BcA, H_N, U_N);
        // r0 = g1@(W2@Wg) + bc   (e-GEMM eliminated)
        bgemm_k<0, BEP_P><<<dim3(BcA / 128, 2), blk, 0, stream>>>(
            g1, nullptr, WcT_h, bc, nullptr, r0b, nullptr, nullptr, nullptr,
            BcA, U_N, H_N);
        // recon, dr0 (in-place over r0b) + dr0^T
        ln_bf_k<<<dim3(BcA / 4), blk, 0, stream>>>(r0b, phic, gamma, beta,
                                                   recon_bf + off * U_N, r0b,
                                                   drT, BcA);
        // da = (dr0 @ Wc^T) * gp -> daT ; db1 += colsum (fused).  de-GEMM gone.
        bgemm_k<0, BEP_DAT><<<dim3(BcA / 128, 8), blk, 0, stream>>>(
            r0b, nullptr, Wcs_h, nullptr, gp, nullptr, daT, nullptr, db1,
            BcA, H_N, U_N);
        // cs2 += colsum(dr0)  (for db2 = cs2 @ Wg^T)
        colsum_rm_k<<<dim3(32), blk, 0, stream>>>(r0b, cs2, BcA);
        // G2 += g1T·dr0T   (dW2 = G2 @ Wg^T finalized later)
        wgrad_k<<<dim3(8, 2, Z), blk, 0, stream>>>(g1T, drT, G2, H_N, U_N,
                                                   BcA, 0, BcA, 0, KC);
        // dW1 += phiT·daT
        wgrad_k<<<dim3(2, 8, Z), blk, 0, stream>>>(phiT_bf, daT, dW1, U_N, H_N,
                                                   B_N, (int)off, BcA, 0, KC);
    }

    // ---- Phase B: finalize grads + updated params ----
    dw2f_k<<<dim3(1024), blk, 0, stream>>>(G2, W_g, dW2f);
    db2f_k<<<dim3(1), blk, 0, stream>>>(cs2, W_g, db2f);
    bupd_k<<<dim3(5), blk, 0, stream>>>(b1, db1, b2, db2f, b1u, b2u);
    tupd_k<<<dim3(4, 16), blk, 0, stream>>>(W1, dW1, W1uT_h, W1uT_l, 256, 1024);
    tupd_k<<<dim3(16, 4), blk, 0, stream>>>(W2, dW2f, W2uT_h, W2uT_l, 1024, 256);

    // ---- Phase C: 3-pass forward, packed hi|lo threaded between GEMMs ----
    for (int c = 0; c < GC; c++) {
        const size_t off = (size_t)c * BcC;
        // psi = [x|h] @ W_psi + b_psi -> packed
        mgemm_k<1, 0, EPI_NONE, 1><<<dim3(BcC / 128, 2), blk, 0, stream>>>(
            x + off * 256, h_prev + off * U_N, nullptr,
            WpsiT_h, WpsiT_l, b_psi, nullptr,
            nullptr, psi_p, BcC, U_N, 512);
        // h2 = gelu(psi @ W1u + b1u) -> packed
        mgemm_k<0, 1, EPI_GELU, 1><<<dim3(BcC / 128, 8), blk, 0, stream>>>(
            nullptr, nullptr, psi_p,
            W1uT_h, W1uT_l, b1u, nullptr,
            nullptr, h2_p, BcC, H_N, U_N);
        // feat = h2 @ W2u + b2u + 0.1*recon -> packed
        mgemm_k<0, 1, EPI_ADDS, 1><<<dim3(BcC / 128, 2), blk, 0, stream>>>(
            nullptr, nullptr, h2_p,
            W2uT_h, W2uT_l, b2u, recon_bf + off * U_N,
            nullptr, feat_p, BcC, U_N, H_N);
        // out = feat @ W_h + h_bias (fp32)
        mgemm_k<0, 1, EPI_NONE, 0><<<dim3(BcC / 128, 2), blk, 0, stream>>>(
            nullptr, nullptr, feat_p,
            WhT_h, WhT_l, h_bias, nullptr,
            out + off * U_N, nullptr, BcC, U_N, U_N);
    }
}

// Round 15
// 925.974 us; speedup vs baseline: 1.1284x; 1.1284x over previous
//
#include <hip/hip_runtime.h>
#include <math.h>

#define B_N 32768
#define U_N 256
#define H_N 1024
#define LR_C 0.01f
#define EPS_C 1e-3f

typedef unsigned short ushort_t;
typedef unsigned int uint_t;
using frag8 = __attribute__((ext_vector_type(8))) short;   // 8 bf16 = 4 VGPR
using f32x4 = __attribute__((ext_vector_type(4))) float;   // MFMA acc

// Branchless erf, Abramowitz-Stegun 7.1.26: |abs err| <= 1.5e-7.
__device__ __forceinline__ float erf_fast(float y) {
    float ay = fabsf(y);
    float t = __builtin_amdgcn_rcpf(fmaf(0.3275911f, ay, 1.0f));
    float p = fmaf(1.061405429f, t, -1.453152027f);
    p = fmaf(p, t, 1.421413741f);
    p = fmaf(p, t, -0.284496736f);
    p = fmaf(p, t, 0.254829592f);
    p = p * t;
    float e = __expf(-ay * ay);
    float r = fmaf(-p, e, 1.0f);
    return copysignf(r, y);
}
__device__ __forceinline__ float gelu_f(float x) {
    return 0.5f * x * (1.0f + erf_fast(x * 0.7071067811865475f));
}
// Fused gelu+dgelu: shares the poly AND the exp (exp(-ay^2) == exp(-x^2/2)).
__device__ __forceinline__ void gelu_pair(float x, float& g, float& d) {
    float ay = fabsf(x) * 0.7071067811865475f;
    float t = __builtin_amdgcn_rcpf(fmaf(0.3275911f, ay, 1.0f));
    float p = fmaf(1.061405429f, t, -1.453152027f);
    p = fmaf(p, t, 1.421413741f);
    p = fmaf(p, t, -0.284496736f);
    p = fmaf(p, t, 0.254829592f);
    p = p * t;
    float e = __expf(-ay * ay);
    float er = copysignf(fmaf(-p, e, 1.0f), x);
    float c = 0.5f * (1.0f + er);
    g = x * c;
    d = fmaf(x * 0.3989422804014327f, e, c);
}
__device__ __forceinline__ void splitf(float v, ushort_t& h, ushort_t& l) {
    uint_t u = __float_as_uint(v);
    h = (ushort_t)(u >> 16);
    float r = v - __uint_as_float(u & 0xFFFF0000u);
    uint_t ru = __float_as_uint(r);
    l = (ushort_t)((ru + 0x7FFFu + ((ru >> 16) & 1u)) >> 16);
}
__device__ __forceinline__ ushort_t cvt_rne(float v) {
    uint_t u = __float_as_uint(v);
    return (ushort_t)((u + 0x7FFFu + ((u >> 16) & 1u)) >> 16);
}
__device__ __forceinline__ float bf2f(ushort_t u) {
    return __uint_as_float((uint_t)u << 16);
}
// pa = packed (h<<16)|l for k=2i, pb for k=2i+1 -> hw/lw = bf16x2 hi/lo words
__device__ __forceinline__ void unpack2(uint_t pa, uint_t pb, uint_t& hw, uint_t& lw) {
    hw = __builtin_amdgcn_perm(pb, pa, 0x07060302u);  // [pa.h, pb.h]
    lw = __builtin_amdgcn_perm(pb, pa, 0x05040100u);  // [pa.l, pb.l]
}
// Weight-plane chunk swizzle: element (n,k) of a [N,K] k-major plane lives at
// n*K + (k&~31) | ((((k>>3)&3) ^ ((n>>1)&3))<<3) | (k&7).  16B chunks XOR'd
// within each 64B (32-elem) row-tile so a LINEAR global_load_lds copy yields
// bank-conflict-free ds_read_b128 fragment reads (2 lanes/bank-group = free).
__device__ __forceinline__ size_t swz(int n, int k, int K) {
    return (size_t)n * K +
           (size_t)((k & ~31) | ((((k >> 3) & 3) ^ ((n >> 1) & 3)) << 3) | (k & 7));
}
// 16B global -> LDS DMA (dest = wave-uniform base + lane*16)
__device__ __forceinline__ void gload16(const ushort_t* g, ushort_t* l) {
    __builtin_amdgcn_global_load_lds(
        (const __attribute__((address_space(1))) void*)g,
        (__attribute__((address_space(3))) void*)l, 16, 0, 0);
}

#define EPI_NONE 0
#define EPI_GELU 1
#define EPI_ADDS 3

// bgemm epilogue modes
#define BEP_P   0   // bf16 row-major out
#define BEP_PT  1   // bf16 row-major + col-major [N,M]
#define BEP_A1  2   // g1=gelu rm + gp=dgelu rm + g1T ct
#define BEP_DAT 3   // acc * gp(bf16) -> col-major only

// ---------------------------------------------------------------------------
// 3-pass split-bf16 GEMM (fp32-class). Phase C only.
// B planes (swizzled weights) staged via global_load_lds into unpadded LDS;
// A staged through registers into padded LDS (unpack / split on the fly).
// ---------------------------------------------------------------------------
template<int ACONCAT, int APACK, int EPI, int OPACK>
__global__ __launch_bounds__(256)
void mgemm_k(const float* A, const float* A2, const uint_t* __restrict__ AP,
             const ushort_t* __restrict__ BTh, const ushort_t* __restrict__ BTl,
             const float* __restrict__ bias, const ushort_t* __restrict__ Xr,
             float* C, uint_t* Cp,
             int M, int N, int K)
{
    __shared__ ushort_t Ah[128 * 40], Al[128 * 40];
    __shared__ ushort_t Bh[128 * 32], Bl[128 * 32];
    const int tid = threadIdx.x;
    const int m0 = blockIdx.x * 128, n0 = blockIdx.y * 128;
    const int lane = tid & 63, w = tid >> 6;
    const int wm = (w & 1) * 64, wn = (w >> 1) * 64;
    const int fr = lane & 15, fq = lane >> 4;
    const int sr = tid >> 1;
    const int sk = (tid & 1) * 16;

    f32x4 acc[4][4];
    #pragma unroll
    for (int i = 0; i < 4; i++)
        #pragma unroll
        for (int j = 0; j < 4; j++) acc[i][j] = (f32x4){0.f, 0.f, 0.f, 0.f};

    for (int k0 = 0; k0 < K; k0 += 32) {
        // ---- B: async DMA, linear LDS (source pre-swizzled) ----
        {
            const int r0w = w * 32;
            const size_t so = (size_t)(n0 + r0w + (lane >> 2)) * K + k0 + ((lane & 3) << 3);
            gload16(&BTh[so],                  &Bh[r0w * 32]);
            gload16(&BTh[so + (size_t)16 * K], &Bh[(r0w + 16) * 32]);
            gload16(&BTl[so],                  &Bl[r0w * 32]);
            gload16(&BTl[so + (size_t)16 * K], &Bl[(r0w + 16) * 32]);
        }
        // ---- A: register staging ----
        if (APACK) {
            const uint_t* ap = AP + (size_t)(m0 + sr) * K + k0 + sk;
            uint4 p0 = *(const uint4*)(ap);
            uint4 p1 = *(const uint4*)(ap + 4);
            uint4 p2 = *(const uint4*)(ap + 8);
            uint4 p3 = *(const uint4*)(ap + 12);
            uint4 h0, h1, l0, l1;
            unpack2(p0.x, p0.y, h0.x, l0.x); unpack2(p0.z, p0.w, h0.y, l0.y);
            unpack2(p1.x, p1.y, h0.z, l0.z); unpack2(p1.z, p1.w, h0.w, l0.w);
            unpack2(p2.x, p2.y, h1.x, l1.x); unpack2(p2.z, p2.w, h1.y, l1.y);
            unpack2(p3.x, p3.y, h1.z, l1.z); unpack2(p3.z, p3.w, h1.w, l1.w);
            *(uint4*)&Ah[sr * 40 + sk]     = h0;
            *(uint4*)&Ah[sr * 40 + sk + 8] = h1;
            *(uint4*)&Al[sr * 40 + sk]     = l0;
            *(uint4*)&Al[sr * 40 + sk + 8] = l1;
        } else {
            #pragma unroll
            for (int g = 0; g < 2; g++) {
                uint4 qh, qa;
                uint_t ph[4], pl[4];
                #pragma unroll
                for (int c = 0; c < 2; c++) {
                    const int ak = k0 + sk + g * 8 + c * 4;
                    const float* ap;
                    if (ACONCAT) ap = (ak < 256) ? (A + (size_t)(m0 + sr) * 256 + ak)
                                                 : (A2 + (size_t)(m0 + sr) * 256 + (ak - 256));
                    else         ap = A + (size_t)(m0 + sr) * K + ak;
                    float4 v = *(const float4*)ap;
                    ushort_t h0,h1,h2,h3,l0,l1,l2,l3;
                    splitf(v.x,h0,l0); splitf(v.y,h1,l1); splitf(v.z,h2,l2); splitf(v.w,h3,l3);
                    ph[c*2]   = (uint_t)h0 | ((uint_t)h1 << 16);
                    ph[c*2+1] = (uint_t)h2 | ((uint_t)h3 << 16);
                    pl[c*2]   = (uint_t)l0 | ((uint_t)l1 << 16);
                    pl[c*2+1] = (uint_t)l2 | ((uint_t)l3 << 16);
                }
                qh.x = ph[0]; qh.y = ph[1]; qh.z = ph[2]; qh.w = ph[3];
                qa.x = pl[0]; qa.y = pl[1]; qa.z = pl[2]; qa.w = pl[3];
                *(uint4*)&Ah[sr * 40 + sk + g * 8] = qh;
                *(uint4*)&Al[sr * 40 + sk + g * 8] = qa;
            }
        }
        __syncthreads();

        frag8 afh[4], afl[4], bfh[4], bfl[4];
        #pragma unroll
        for (int i = 0; i < 4; i++) {
            const int ar = wm + i * 16 + fr;
            afh[i] = *(frag8*)&Ah[ar * 40 + fq * 8];
            afl[i] = *(frag8*)&Al[ar * 40 + fq * 8];
        }
        #pragma unroll
        for (int j = 0; j < 4; j++) {
            const int br = wn + j * 16 + fr;
            const int bs = br * 32 + ((fq ^ ((br >> 1) & 3)) << 3);
            bfh[j] = *(frag8*)&Bh[bs];
            bfl[j] = *(frag8*)&Bl[bs];
        }
        #pragma unroll
        for (int i = 0; i < 4; i++)
            #pragma unroll
            for (int j = 0; j < 4; j++) {
                acc[i][j] = __builtin_amdgcn_mfma_f32_16x16x32_bf16(afh[i], bfh[j], acc[i][j], 0, 0, 0);
                acc[i][j] = __builtin_amdgcn_mfma_f32_16x16x32_bf16(afh[i], bfl[j], acc[i][j], 0, 0, 0);
                acc[i][j] = __builtin_amdgcn_mfma_f32_16x16x32_bf16(afl[i], bfh[j], acc[i][j], 0, 0, 0);
            }
        __syncthreads();
    }

    float bv[4] = {0.f, 0.f, 0.f, 0.f};
    if (bias != nullptr)
        #pragma unroll
        for (int j = 0; j < 4; j++) bv[j] = bias[n0 + wn + j * 16 + fr];
    #pragma unroll
    for (int i = 0; i < 4; i++)
        #pragma unroll
        for (int j = 0; j < 4; j++) {
            const int col = n0 + wn + j * 16 + fr;
            #pragma unroll
            for (int r = 0; r < 4; r++) {
                const int row = m0 + wm + i * 16 + fq * 4 + r;
                const size_t off = (size_t)row * N + col;
                float c = acc[i][j][r] + bv[j];
                if (EPI == EPI_GELU)      c = gelu_f(c);
                else if (EPI == EPI_ADDS) c = c + 0.1f * bf2f(Xr[off]);
                if (OPACK) {
                    ushort_t h, l;
                    splitf(c, h, l);
                    Cp[off] = ((uint_t)h << 16) | (uint_t)l;
                } else {
                    C[off] = c;
                }
            }
        }
}

// ---------------------------------------------------------------------------
// 1-pass bf16 GEMM (Phase A). B plane (swizzled weights) via global_load_lds;
// A through registers into padded LDS. Optional fused column-sum (dbsum).
// ---------------------------------------------------------------------------
template<int ACONCAT, int BEP>
__global__ __launch_bounds__(256)
void bgemm_k(const void* Av, const float* A2f, const ushort_t* __restrict__ BTh,
             const float* __restrict__ bias, const ushort_t* __restrict__ GpIn,
             ushort_t* Crm, ushort_t* Cct, ushort_t* GpOut, float* dbsum,
             int M, int N, int K)
{
    __shared__ ushort_t Ah[128 * 40];
    __shared__ ushort_t Bh[128 * 32];
    const int tid = threadIdx.x;
    const int m0 = blockIdx.x * 128, n0 = blockIdx.y * 128;
    const int lane = tid & 63, w = tid >> 6;
    const int wm = (w & 1) * 64, wn = (w >> 1) * 64;
    const int fr = lane & 15, fq = lane >> 4;
    const int sr = tid >> 1;
    const int sk = (tid & 1) * 16;

    f32x4 acc[4][4];
    #pragma unroll
    for (int i = 0; i < 4; i++)
        #pragma unroll
        for (int j = 0; j < 4; j++) acc[i][j] = (f32x4){0.f, 0.f, 0.f, 0.f};

    for (int k0 = 0; k0 < K; k0 += 32) {
        // ---- B: async DMA ----
        {
            const int r0w = w * 32;
            const size_t so = (size_t)(n0 + r0w + (lane >> 2)) * K + k0 + ((lane & 3) << 3);
            gload16(&BTh[so],                  &Bh[r0w * 32]);
            gload16(&BTh[so + (size_t)16 * K], &Bh[(r0w + 16) * 32]);
        }
        // ---- A ----
        if (ACONCAT) {
            const float* A = (const float*)Av;
            #pragma unroll
            for (int g = 0; g < 2; g++) {
                uint_t ph[4];
                #pragma unroll
                for (int c = 0; c < 2; c++) {
                    const int ak = k0 + sk + g * 8 + c * 4;
                    const float* ap = (ak < 256) ? (A + (size_t)(m0 + sr) * 256 + ak)
                                                 : (A2f + (size_t)(m0 + sr) * 256 + (ak - 256));
                    float4 v = *(const float4*)ap;
                    ph[c*2]   = (uint_t)cvt_rne(v.x) | ((uint_t)cvt_rne(v.y) << 16);
                    ph[c*2+1] = (uint_t)cvt_rne(v.z) | ((uint_t)cvt_rne(v.w) << 16);
                }
                uint4 q; q.x = ph[0]; q.y = ph[1]; q.z = ph[2]; q.w = ph[3];
                *(uint4*)&Ah[sr * 40 + sk + g * 8] = q;
            }
        } else {
            const ushort_t* A = (const ushort_t*)Av;
            const size_t ao = (size_t)(m0 + sr) * K + k0 + sk;
            *(uint4*)&Ah[sr * 40 + sk]     = *(const uint4*)&A[ao];
            *(uint4*)&Ah[sr * 40 + sk + 8] = *(const uint4*)&A[ao + 8];
        }
        __syncthreads();

        frag8 af[4], bf[4];
        #pragma unroll
        for (int i = 0; i < 4; i++) af[i] = *(frag8*)&Ah[(wm + i * 16 + fr) * 40 + fq * 8];
        #pragma unroll
        for (int j = 0; j < 4; j++) {
            const int br = wn + j * 16 + fr;
            bf[j] = *(frag8*)&Bh[br * 32 + ((fq ^ ((br >> 1) & 3)) << 3)];
        }
        #pragma unroll
        for (int i = 0; i < 4; i++)
            #pragma unroll
            for (int j = 0; j < 4; j++)
                acc[i][j] = __builtin_amdgcn_mfma_f32_16x16x32_bf16(af[i], bf[j], acc[i][j], 0, 0, 0);
        __syncthreads();
    }

    float bv[4] = {0.f, 0.f, 0.f, 0.f};
    if (bias != nullptr)
        #pragma unroll
        for (int j = 0; j < 4; j++) bv[j] = bias[n0 + wn + j * 16 + fr];
    float cs[4] = {0.f, 0.f, 0.f, 0.f};
    #pragma unroll
    for (int i = 0; i < 4; i++)
        #pragma unroll
        for (int j = 0; j < 4; j++) {
            const int col = n0 + wn + j * 16 + fr;
            const int rowb = m0 + wm + i * 16 + fq * 4;
            float v[4];
            #pragma unroll
            for (int r = 0; r < 4; r++) v[r] = acc[i][j][r] + bv[j];
            if (BEP == BEP_A1) {
                ushort_t gc[4];
                #pragma unroll
                for (int r = 0; r < 4; r++) {
                    float g, d;
                    gelu_pair(v[r], g, d);
                    gc[r] = cvt_rne(g);
                    Crm[(size_t)(rowb + r) * N + col] = gc[r];
                    GpOut[(size_t)(rowb + r) * N + col] = cvt_rne(d);
                }
                uint_t p0 = (uint_t)gc[0] | ((uint_t)gc[1] << 16);
                uint_t p1 = (uint_t)gc[2] | ((uint_t)gc[3] << 16);
                *(uint2*)&Cct[(size_t)col * M + rowb] = (uint2){p0, p1};
            } else if (BEP == BEP_DAT) {
                ushort_t dc[4];
                #pragma unroll
                for (int r = 0; r < 4; r++) {
                    float pr = v[r] * bf2f(GpIn[(size_t)(rowb + r) * N + col]);
                    dc[r] = cvt_rne(pr);
                    cs[j] += pr;
                }
                uint_t p0 = (uint_t)dc[0] | ((uint_t)dc[1] << 16);
                uint_t p1 = (uint_t)dc[2] | ((uint_t)dc[3] << 16);
                *(uint2*)&Cct[(size_t)col * M + rowb] = (uint2){p0, p1};
            } else {
                ushort_t cc[4];
                #pragma unroll
                for (int r = 0; r < 4; r++) {
                    cc[r] = cvt_rne(v[r]);
                    Crm[(size_t)(rowb + r) * N + col] = cc[r];
                }
                cs[j] += v[0] + v[1] + v[2] + v[3];
                if (BEP == BEP_PT) {
                    uint_t p0 = (uint_t)cc[0] | ((uint_t)cc[1] << 16);
                    uint_t p1 = (uint_t)cc[2] | ((uint_t)cc[3] << 16);
                    *(uint2*)&Cct[(size_t)col * M + rowb] = (uint2){p0, p1};
                }
            }
        }
    if (dbsum != nullptr) {
        #pragma unroll
        for (int j = 0; j < 4; j++) {
            float s = cs[j];
            s += __shfl_xor(s, 16);
            s += __shfl_xor(s, 32);
            if (fq == 0) atomicAdd(&dbsum[n0 + wn + j * 16 + fr], s);
        }
    }
}

// ---------------------------------------------------------------------------
// Weight-grad: C[M,N] += AT[M,:]·BT[N,:] over split-K chunk. Both k-major bf16.
// ---------------------------------------------------------------------------
__global__ __launch_bounds__(256)
void wgrad_k(const ushort_t* __restrict__ AT, const ushort_t* __restrict__ BTt,
             float* C, int M, int N, int KA, int kofsA, int KB, int kofsB, int KC)
{
    __shared__ ushort_t Ah[128 * 40];
    __shared__ ushort_t Bh[128 * 40];
    const int tid = threadIdx.x;
    const int m0 = blockIdx.x * 128, n0 = blockIdx.y * 128;
    const int kbA = kofsA + blockIdx.z * KC;
    const int kbB = kofsB + blockIdx.z * KC;
    const int lane = tid & 63, w = tid >> 6;
    const int wm = (w & 1) * 64, wn = (w >> 1) * 64;
    const int fr = lane & 15, fq = lane >> 4;
    const int sr = tid >> 1;
    const int sk = (tid & 1) * 16;

    f32x4 acc[4][4];
    #pragma unroll
    for (int i = 0; i < 4; i++)
        #pragma unroll
        for (int j = 0; j < 4; j++) acc[i][j] = (f32x4){0.f, 0.f, 0.f, 0.f};

    for (int k0 = 0; k0 < KC; k0 += 32) {
        const size_t ao = (size_t)(m0 + sr) * KA + kbA + k0 + sk;
        *(uint4*)&Ah[sr * 40 + sk]     = *(const uint4*)&AT[ao];
        *(uint4*)&Ah[sr * 40 + sk + 8] = *(const uint4*)&AT[ao + 8];
        const size_t bo = (size_t)(n0 + sr) * KB + kbB + k0 + sk;
        *(uint4*)&Bh[sr * 40 + sk]     = *(const uint4*)&BTt[bo];
        *(uint4*)&Bh[sr * 40 + sk + 8] = *(const uint4*)&BTt[bo + 8];
        __syncthreads();

        frag8 af[4], bf[4];
        #pragma unroll
        for (int i = 0; i < 4; i++) af[i] = *(frag8*)&Ah[(wm + i * 16 + fr) * 40 + fq * 8];
        #pragma unroll
        for (int j = 0; j < 4; j++) bf[j] = *(frag8*)&Bh[(wn + j * 16 + fr) * 40 + fq * 8];
        #pragma unroll
        for (int i = 0; i < 4; i++)
            #pragma unroll
            for (int j = 0; j < 4; j++)
                acc[i][j] = __builtin_amdgcn_mfma_f32_16x16x32_bf16(af[i], bf[j], acc[i][j], 0, 0, 0);
        __syncthreads();
    }
    #pragma unroll
    for (int i = 0; i < 4; i++)
        #pragma unroll
        for (int j = 0; j < 4; j++) {
            const int col = n0 + wn + j * 16 + fr;
            #pragma unroll
            for (int r = 0; r < 4; r++) {
                const int row = m0 + wm + i * 16 + fq * 4 + r;
                atomicAdd(&C[(size_t)row * N + col], acc[i][j][r]);
            }
        }
}

// LayerNorm fwd + dL/dr0, bf16 in/out (dr0 may alias r0)
__global__ __launch_bounds__(256)
void ln_bf_k(const ushort_t* r0, const ushort_t* __restrict__ phi,
             const float* __restrict__ gamma, const float* __restrict__ beta,
             ushort_t* recon, ushort_t* dr0)
{
    const int lane = threadIdx.x & 63;
    const int wv = threadIdx.x >> 6;
    const int row = blockIdx.x * 4 + wv;
    const size_t base = (size_t)row * U_N + (lane << 2);

    uint2 xu = *(const uint2*)(r0 + base);
    uint2 pu = *(const uint2*)(phi + base);
    float xs[4] = { bf2f((ushort_t)(xu.x & 0xFFFF)), bf2f((ushort_t)(xu.x >> 16)),
                    bf2f((ushort_t)(xu.y & 0xFFFF)), bf2f((ushort_t)(xu.y >> 16)) };
    float ps[4] = { bf2f((ushort_t)(pu.x & 0xFFFF)), bf2f((ushort_t)(pu.x >> 16)),
                    bf2f((ushort_t)(pu.y & 0xFFFF)), bf2f((ushort_t)(pu.y >> 16)) };
    float s = xs[0] + xs[1] + xs[2] + xs[3];
    float sq = xs[0]*xs[0] + xs[1]*xs[1] + xs[2]*xs[2] + xs[3]*xs[3];
    #pragma unroll
    for (int o = 32; o > 0; o >>= 1) { s += __shfl_xor(s, o); sq += __shfl_xor(sq, o); }
    const float m   = s * (1.0f / U_N);
    const float var = sq * (1.0f / U_N) - m * m;
    const float inv = rsqrtf(var + EPS_C);

    float4 gv = *(const float4*)(gamma + (lane << 2));
    float4 bvv = *(const float4*)(beta + (lane << 2));
    float gs[4] = {gv.x, gv.y, gv.z, gv.w};
    float bs[4] = {bvv.x, bvv.y, bvv.z, bvv.w};
    float rh[4], dh[4], rc[4];
    float s1 = 0.f, s2 = 0.f;
    const float gscale = 2.0f / ((float)B_N * (float)U_N);
    #pragma unroll
    for (int j = 0; j < 4; j++) {
        rh[j] = (xs[j] - m) * inv;
        rc[j] = rh[j] * gs[j] + bs[j];
        float g2 = gscale * (rc[j] - ps[j]);
        dh[j] = g2 * gs[j];
        s1 += dh[j];
        s2 += dh[j] * rh[j];
    }
    #pragma unroll
    for (int o = 32; o > 0; o >>= 1) { s1 += __shfl_xor(s1, o); s2 += __shfl_xor(s2, o); }
    const float mu1 = s1 * (1.0f / U_N);
    const float mu2 = s2 * (1.0f / U_N);
    ushort_t oc[4], dc[4];
    #pragma unroll
    for (int j = 0; j < 4; j++) {
        oc[j] = cvt_rne(rc[j]);
        dc[j] = cvt_rne(inv * (dh[j] - mu1 - rh[j] * mu2));
    }
    *(uint2*)(recon + base) = (uint2){ (uint_t)oc[0] | ((uint_t)oc[1] << 16),
                                       (uint_t)oc[2] | ((uint_t)oc[3] << 16) };
    *(uint2*)(dr0 + base)   = (uint2){ (uint_t)dc[0] | ((uint_t)dc[1] << 16),
                                       (uint_t)dc[2] | ((uint_t)dc[3] << 16) };
}

// Tiled bf16 transpose: S [rows,256] row-major -> D [256,rows] (coalesced R/W)
__global__ __launch_bounds__(256)
void tr_bf_k(const ushort_t* __restrict__ S, ushort_t* __restrict__ D, int R)
{
    __shared__ ushort_t t[64][65];
    const int tid = threadIdx.x;
    const int r0 = blockIdx.x * 64, c0 = blockIdx.y * 64;
    const int c = tid & 63, rb = (tid >> 6) * 16;
    for (int i = 0; i < 16; i++)
        t[rb + i][c] = S[(size_t)(r0 + rb + i) * 256 + c0 + c];
    __syncthreads();
    const int orr = tid & 63, ob = (tid >> 6) * 16;
    for (int i = 0; i < 16; i++)
        D[(size_t)(c0 + ob + i) * R + r0 + orr] = t[orr][ob + i];
}

// column sums of row-major bf16 D [rows, 256] -> cs[256] (atomic +=)
__global__ __launch_bounds__(256)
void colsum_rm_k(const ushort_t* __restrict__ D, float* cs, int rows)
{
    __shared__ float red[4][256];
    const int tid = threadIdx.x;
    const int cg = (tid & 63) << 2;     // col group base
    const int rg = tid >> 6;            // row phase
    float a0 = 0.f, a1 = 0.f, a2 = 0.f, a3 = 0.f;
    const int rpb = rows / gridDim.x;
    const int r0 = blockIdx.x * rpb;
    for (int r = r0 + rg; r < r0 + rpb; r += 4) {
        uint2 q = *(const uint2*)&D[(size_t)r * 256 + cg];
        a0 += bf2f((ushort_t)(q.x & 0xFFFF)); a1 += bf2f((ushort_t)(q.x >> 16));
        a2 += bf2f((ushort_t)(q.y & 0xFFFF)); a3 += bf2f((ushort_t)(q.y >> 16));
    }
    red[rg][cg]     = a0;
    red[rg][cg + 1] = a1;
    red[rg][cg + 2] = a2;
    red[rg][cg + 3] = a3;
    __syncthreads();
    const int c = tid;
    float ssum = red[0][c] + red[1][c] + red[2][c] + red[3][c];
    atomicAdd(&cs[c], ssum);
}

// transpose + split: W [R,C] fp32 -> Th (+Tl if HASL) [C,R], chunk-swizzled
template<int HASL>
__global__ __launch_bounds__(256)
void tsplit_k(const float* __restrict__ W, ushort_t* __restrict__ Th,
              ushort_t* __restrict__ Tl, int R, int C)
{
    __shared__ float t[64][65];
    const int tid = threadIdx.x;
    const int R0 = blockIdx.x * 64, C0 = blockIdx.y * 64;
    const int c = tid & 63, rb = (tid >> 6) * 16;
    for (int i = 0; i < 16; i++)
        t[rb + i][c] = W[(size_t)(R0 + rb + i) * C + C0 + c];
    __syncthreads();
    const int orr = tid & 63, ob = (tid >> 6) * 16;
    for (int i = 0; i < 16; i++) {
        const int oc = ob + i;
        ushort_t h, l;
        splitf(t[orr][oc], h, l);
        const size_t d = swz(C0 + oc, R0 + orr, R);
        Th[d] = h;
        if (HASL) Tl[d] = l;
    }
}

// transpose + SGD update + split (hi+lo), chunk-swizzled
__global__ __launch_bounds__(256)
void tupd_k(const float* __restrict__ W, const float* __restrict__ dW,
            ushort_t* __restrict__ Th, ushort_t* __restrict__ Tl, int R, int C)
{
    __shared__ float t[64][65];
    const int tid = threadIdx.x;
    const int R0 = blockIdx.x * 64, C0 = blockIdx.y * 64;
    const int c = tid & 63, rb = (tid >> 6) * 16;
    for (int i = 0; i < 16; i++) {
        const size_t o = (size_t)(R0 + rb + i) * C + C0 + c;
        t[rb + i][c] = W[o] - LR_C * dW[o];
    }
    __syncthreads();
    const int orr = tid & 63, ob = (tid >> 6) * 16;
    for (int i = 0; i < 16; i++) {
        const int oc = ob + i;
        ushort_t h, l;
        splitf(t[orr][oc], h, l);
        const size_t d = swz(C0 + oc, R0 + orr, R);
        Th[d] = h;
        Tl[d] = l;
    }
}

// elementwise hi-plane convert, chunk-swizzled. Row length fixed at 256.
__global__ __launch_bounds__(256)
void scvt_k(const float* __restrict__ W, ushort_t* __restrict__ Th, int n4)
{
    const int i = blockIdx.x * 256 + threadIdx.x;
    if (i >= n4) return;
    float4 v = *(const float4*)(W + (size_t)i * 4);
    const int f = i * 4;
    const int row = f >> 8, col = f & 255;
    uint2 ph;
    ph.x = (uint_t)cvt_rne(v.x) | ((uint_t)cvt_rne(v.y) << 16);
    ph.y = (uint_t)cvt_rne(v.z) | ((uint_t)cvt_rne(v.w) << 16);
    *(uint2*)&Th[swz(row, col, 256)] = ph;
}

// Wc = W2 @ Wg (fp32): W2 [1024,256], Wg [256,256] -> Wc [1024,256]
__global__ __launch_bounds__(256)
void wcmul_k(const float* __restrict__ W2, const float* __restrict__ Wg,
             float* __restrict__ Wc)
{
    const int i = blockIdx.x;
    const int j = threadIdx.x;
    float s = 0.f;
    for (int k = 0; k < 256; k++)
        s = fmaf(W2[i * 256 + k], Wg[k * 256 + j], s);
    Wc[i * 256 + j] = s;
}
// bc = b2 @ Wg + g_bias
__global__ __launch_bounds__(256)
void bcmul_k(const float* __restrict__ b2, const float* __restrict__ Wg,
             const float* __restrict__ gb, float* __restrict__ bc)
{
    const int j = threadIdx.x;
    float s = gb[j];
    for (int k = 0; k < 256; k++)
        s = fmaf(b2[k], Wg[k * 256 + j], s);
    bc[j] = s;
}
// dW2 = G2 @ Wg^T : G2 [1024,256], Wg [256,256] -> dW2[i,u] = sum_v G2[i,v]*Wg[u,v]
__global__ __launch_bounds__(256)
void dw2f_k(const float* __restrict__ G2, const float* __restrict__ Wg,
            float* __restrict__ dW2)
{
    const int i = blockIdx.x;
    const int u = threadIdx.x;
    float s = 0.f;
    for (int v = 0; v < 256; v++)
        s = fmaf(G2[i * 256 + v], Wg[u * 256 + v], s);
    dW2[i * 256 + u] = s;
}
// db2 = cs2 @ Wg^T : db2[u] = sum_v cs2[v]*Wg[u,v]
__global__ __launch_bounds__(256)
void db2f_k(const float* __restrict__ cs2, const float* __restrict__ Wg,
            float* __restrict__ db2)
{
    const int u = threadIdx.x;
    float s = 0.f;
    for (int v = 0; v < 256; v++)
        s = fmaf(cs2[v], Wg[u * 256 + v], s);
    db2[u] = s;
}

__global__ __launch_bounds__(256)
void bupd_k(const float* __restrict__ b1, const float* __restrict__ db1,
            const float* __restrict__ b2, const float* __restrict__ db2,
            float* __restrict__ b1u, float* __restrict__ b2u)
{
    const int i = blockIdx.x * 256 + threadIdx.x;
    if (i < H_N) b1u[i] = b1[i] - LR_C * db1[i];
    else if (i < H_N + U_N) b2u[i - H_N] = b2[i - H_N] - LR_C * db2[i - H_N];
}

extern "C" void kernel_launch(void* const* d_in, const int* in_sizes, int n_in,
                              void* d_out, int out_size, void* d_ws, size_t ws_size,
                              hipStream_t stream)
{
    const float* x      = (const float*)d_in[0];
    const float* h_prev = (const float*)d_in[1];
    const float* W_phi  = (const float*)d_in[2];
    const float* b_phi  = (const float*)d_in[3];
    const float* W_psi  = (const float*)d_in[4];
    const float* b_psi  = (const float*)d_in[5];
    const float* W1     = (const float*)d_in[6];
    const float* b1     = (const float*)d_in[7];
    const float* W2     = (const float*)d_in[8];
    const float* b2     = (const float*)d_in[9];
    const float* W_g    = (const float*)d_in[10];
    const float* g_bias = (const float*)d_in[11];
    const float* gamma  = (const float*)d_in[12];
    const float* beta   = (const float*)d_in[13];
    const float* W_h    = (const float*)d_in[14];
    const float* h_bias = (const float*)d_in[15];
    float* out = (float*)d_out;

    const size_t BU = (size_t)B_N * U_N;
    const size_t UH = (size_t)U_N * H_N;

    // ---- fixed allocations ----
    float* ws  = (float*)d_ws;
    float* dW1 = ws;                      // [U,H]
    float* db1 = dW1 + UH;                // [H]
    float* G2  = db1 + H_N;               // [H,U]  (g1^T @ dr0 accumulator)
    float* cs2 = G2 + UH;                 // [U]    (colsum of dr0)
    float* b1u = cs2 + U_N;
    float* b2u = b1u + H_N;
    float* bc  = b2u + U_N;               // [U] fused r0 bias
    float* Wc  = bc + U_N;                // [H,U] fp32 = W2@Wg
    float* dW2f= Wc + UH;                 // [H,U] finalized dW2
    float* db2f= dW2f + UH;               // [U]
    ushort_t* us = (ushort_t*)(((uintptr_t)(db2f + U_N) + 15) & ~(uintptr_t)15);
    // weight planes (all chunk-swizzled)
    ushort_t* WphiT_h = us;                   // [U,512]
    ushort_t* WpsiT_h = WphiT_h + 131072;     ushort_t* WpsiT_l = WpsiT_h + 131072;
    ushort_t* WcT_h   = WpsiT_l + 131072;     // [U,H] = (W2@Wg)^T
    ushort_t* W1T_h   = WcT_h + 262144;       // [H,U]
    ushort_t* Wcs_h   = W1T_h + 262144;       // Wc row-major [H,U]
    ushort_t* W1uT_h  = Wcs_h + 262144;       ushort_t* W1uT_l = W1uT_h + 262144;
    ushort_t* W2uT_h  = W1uT_l + 262144;      ushort_t* W2uT_l = W2uT_h + 262144;
    ushort_t* WhT_h   = W2uT_l + 262144;      ushort_t* WhT_l  = WhT_h + 65536;
    // persistent bf16 activations
    ushort_t* phi_bf  = WhT_l + 65536;        // [B,U]
    ushort_t* phiT_bf = phi_bf + BU;          // [U,B]
    ushort_t* recon_bf= phiT_bf + BU;         // [B,U]
    ushort_t* chunk0  = recon_bf + BU;        // chunk region start
    const size_t P_bytes = (size_t)((char*)chunk0 - (char*)d_ws);

    // ---- chunk sizing ----
    int GA = 2;
    while (GA < 256 && P_bytes + (size_t)(B_N / GA) * 10240 + (1 << 20) > ws_size) GA *= 2;
    size_t region = (size_t)(B_N / GA) * 10240;
    int GC = 1;
    while (GC < 256) {
        size_t cC = (size_t)(B_N / GC) * 6144;
        size_t r = cC > region ? cC : region;
        if (P_bytes + r + (1 << 20) <= ws_size) { region = r; break; }
        GC *= 2;
    }
    const int BcA = B_N / GA;
    const int BcC = B_N / GC;
    const int KC = (BcA >= 8192) ? 512 : ((BcA >= 1024) ? BcA / 16 : BcA);
    const int Z  = BcA / KC;

    // Phase A chunk buffers (bf16)
    ushort_t* g1  = chunk0;                       // [BcA,H]
    ushort_t* gp  = g1  + (size_t)BcA * H_N;      // [BcA,H]
    ushort_t* g1T = gp  + (size_t)BcA * H_N;      // [H,BcA]
    ushort_t* daT = g1T + (size_t)BcA * H_N;      // [H,BcA]
    ushort_t* e_b = daT + (size_t)BcA * H_N;      // [BcA,U]  (unused; layout kept)
    ushort_t* r0b = e_b + (size_t)BcA * U_N;      // [BcA,U]  (r0 -> dr0)
    ushort_t* deb = r0b + (size_t)BcA * U_N;      // [BcA,U]  (unused)
    ushort_t* drT = deb + (size_t)BcA * U_N;      // [U,BcA]  dr0^T
    // Phase C chunk buffers (packed hi|lo words, overlay same region)
    uint_t* psi_p  = (uint_t*)chunk0;             // [BcC,U]
    uint_t* h2_p   = psi_p + (size_t)BcC * U_N;   // [BcC,H]
    uint_t* feat_p = h2_p  + (size_t)BcC * H_N;   // [BcC,U]

    // zero: dW1 [UH], db1 [H], G2 [UH], cs2 [U] (contiguous)
    hipMemsetAsync(dW1, 0, (2 * UH + H_N + U_N) * sizeof(float), stream);

    dim3 blk(256);
    // weight prep (planes stored chunk-swizzled)
    tsplit_k<0><<<dim3(8, 4),  blk, 0, stream>>>(W_phi, WphiT_h, nullptr, 512, 256);
    tsplit_k<1><<<dim3(8, 4),  blk, 0, stream>>>(W_psi, WpsiT_h, WpsiT_l, 512, 256);
    tsplit_k<0><<<dim3(4, 16), blk, 0, stream>>>(W1, W1T_h, nullptr, 256, 1024);
    tsplit_k<1><<<dim3(4, 4),  blk, 0, stream>>>(W_h, WhT_h, WhT_l, 256, 256);
    // Wc = W2@Wg, bc = b2@Wg + g_bias (folds the e-GEMM and de-GEMM away)
    wcmul_k<<<dim3(1024), blk, 0, stream>>>(W2, W_g, Wc);
    bcmul_k<<<dim3(1), blk, 0, stream>>>(b2, W_g, g_bias, bc);
    tsplit_k<0><<<dim3(16, 4), blk, 0, stream>>>(Wc, WcT_h, nullptr, 1024, 256);
    scvt_k<<<dim3(256), blk, 0, stream>>>(Wc, Wcs_h, 65536);

    // phi = [x|h_prev] @ W_phi + b_phi  (1-pass, bf16 out rm + T)
    bgemm_k<1, BEP_PT><<<dim3(B_N / 128, 2), blk, 0, stream>>>(
        x, h_prev, WphiT_h, b_phi, nullptr, phi_bf, phiT_bf, nullptr, nullptr,
        B_N, U_N, 512);

    // ---- Phase A: inner fwd+bwd, 1-pass bf16, chunked ----
    for (int c = 0; c < GA; c++) {
        const size_t off = (size_t)c * BcA;
        const ushort_t* phic = phi_bf + off * U_N;
        // a1 = phi@W1+b1 -> g1(gelu) rm, gp(dgelu) rm, g1T ct
        bgemm_k<0, BEP_A1><<<dim3(BcA / 128, 8), blk, 0, stream>>>(
            phic, nullptr, W1T_h, b1, nullptr, g1, g1T, gp, nullptr, BcA, H_N, U_N);
        // r0 = g1@(W2@Wg) + bc   (e-GEMM eliminated)
        bgemm_k<0, BEP_P><<<dim3(BcA / 128, 2), blk, 0, stream>>>(
            g1, nullptr, WcT_h, bc, nullptr, r0b, nullptr, nullptr, nullptr,
            BcA, U_N, H_N);
        // recon, dr0 (in-place over r0b)
        ln_bf_k<<<dim3(BcA / 4), blk, 0, stream>>>(r0b, phic, gamma, beta,
                                                   recon_bf + off * U_N, r0b);
        // dr0^T via coalesced tiled transpose
        tr_bf_k<<<dim3(BcA / 64, 4), blk, 0, stream>>>(r0b, drT, BcA);
        // da = (dr0 @ Wc^T) * gp -> daT ; db1 += colsum (fused).  de-GEMM gone.
        bgemm_k<0, BEP_DAT><<<dim3(BcA / 128, 8), blk, 0, stream>>>(
            r0b, nullptr, Wcs_h, nullptr, gp, nullptr, daT, nullptr, db1,
            BcA, H_N, U_N);
        // cs2 += colsum(dr0)  (for db2 = cs2 @ Wg^T)
        colsum_rm_k<<<dim3(32), blk, 0, stream>>>(r0b, cs2, BcA);
        // G2 += g1T·dr0T   (dW2 = G2 @ Wg^T finalized later)
        wgrad_k<<<dim3(8, 2, Z), blk, 0, stream>>>(g1T, drT, G2, H_N, U_N,
                                                   BcA, 0, BcA, 0, KC);
        // dW1 += phiT·daT
        wgrad_k<<<dim3(2, 8, Z), blk, 0, stream>>>(phiT_bf, daT, dW1, U_N, H_N,
                                                   B_N, (int)off, BcA, 0, KC);
    }

    // ---- Phase B: finalize grads + updated params ----
    dw2f_k<<<dim3(1024), blk, 0, stream>>>(G2, W_g, dW2f);
    db2f_k<<<dim3(1), blk, 0, stream>>>(cs2, W_g, db2f);
    bupd_k<<<dim3(5), blk, 0, stream>>>(b1, db1, b2, db2f, b1u, b2u);
    tupd_k<<<dim3(4, 16), blk, 0, stream>>>(W1, dW1, W1uT_h, W1uT_l, 256, 1024);
    tupd_k<<<dim3(16, 4), blk, 0, stream>>>(W2, dW2f, W2uT_h, W2uT_l, 1024, 256);

    // ---- Phase C: 3-pass forward, packed hi|lo threaded between GEMMs ----
    for (int c = 0; c < GC; c++) {
        const size_t off = (size_t)c * BcC;
        // psi = [x|h] @ W_psi + b_psi -> packed
        mgemm_k<1, 0, EPI_NONE, 1><<<dim3(BcC / 128, 2), blk, 0, stream>>>(
            x + off * 256, h_prev + off * U_N, nullptr,
            WpsiT_h, WpsiT_l, b_psi, nullptr,
            nullptr, psi_p, BcC, U_N, 512);
        // h2 = gelu(psi @ W1u + b1u) -> packed
        mgemm_k<0, 1, EPI_GELU, 1><<<dim3(BcC / 128, 8), blk, 0, stream>>>(
            nullptr, nullptr, psi_p,
            W1uT_h, W1uT_l, b1u, nullptr,
            nullptr, h2_p, BcC, H_N, U_N);
        // feat = h2 @ W2u + b2u + 0.1*recon -> packed
        mgemm_k<0, 1, EPI_ADDS, 1><<<dim3(BcC / 128, 2), blk, 0, stream>>>(
            nullptr, nullptr, h2_p,
            W2uT_h, W2uT_l, b2u, recon_bf + off * U_N,
            nullptr, feat_p, BcC, U_N, H_N);
        // out = feat @ W_h + h_bias (fp32)
        mgemm_k<0, 1, EPI_NONE, 0><<<dim3(BcC / 128, 2), blk, 0, stream>>>(
            nullptr, nullptr, feat_p,
            WhT_h, WhT_l, h_bias, nullptr,
            out + off * U_N, nullptr, BcC, U_N, U_N);
    }
}

// Round 16
// 844.911 us; speedup vs baseline: 1.2366x; 1.0959x over previous
//
#include <hip/hip_runtime.h>
#include <math.h>

#define B_N 32768
#define U_N 256
#define H_N 1024
#define LR_C 0.01f
#define EPS_C 1e-3f

typedef unsigned short ushort_t;
typedef unsigned int uint_t;
using frag8 = __attribute__((ext_vector_type(8))) short;   // 8 bf16 = 4 VGPR
using f32x4 = __attribute__((ext_vector_type(4))) float;   // MFMA acc

// Branchless erf, Abramowitz-Stegun 7.1.26: |abs err| <= 1.5e-7.
__device__ __forceinline__ float erf_fast(float y) {
    float ay = fabsf(y);
    float t = __builtin_amdgcn_rcpf(fmaf(0.3275911f, ay, 1.0f));
    float p = fmaf(1.061405429f, t, -1.453152027f);
    p = fmaf(p, t, 1.421413741f);
    p = fmaf(p, t, -0.284496736f);
    p = fmaf(p, t, 0.254829592f);
    p = p * t;
    float e = __expf(-ay * ay);
    float r = fmaf(-p, e, 1.0f);
    return copysignf(r, y);
}
__device__ __forceinline__ float gelu_f(float x) {
    return 0.5f * x * (1.0f + erf_fast(x * 0.7071067811865475f));
}
// Fused gelu+dgelu: shares the poly AND the exp (exp(-ay^2) == exp(-x^2/2)).
__device__ __forceinline__ void gelu_pair(float x, float& g, float& d) {
    float ay = fabsf(x) * 0.7071067811865475f;
    float t = __builtin_amdgcn_rcpf(fmaf(0.3275911f, ay, 1.0f));
    float p = fmaf(1.061405429f, t, -1.453152027f);
    p = fmaf(p, t, 1.421413741f);
    p = fmaf(p, t, -0.284496736f);
    p = fmaf(p, t, 0.254829592f);
    p = p * t;
    float e = __expf(-ay * ay);
    float er = copysignf(fmaf(-p, e, 1.0f), x);
    float c = 0.5f * (1.0f + er);
    g = x * c;
    d = fmaf(x * 0.3989422804014327f, e, c);
}
__device__ __forceinline__ void splitf(float v, ushort_t& h, ushort_t& l) {
    uint_t u = __float_as_uint(v);
    h = (ushort_t)(u >> 16);
    float r = v - __uint_as_float(u & 0xFFFF0000u);
    uint_t ru = __float_as_uint(r);
    l = (ushort_t)((ru + 0x7FFFu + ((ru >> 16) & 1u)) >> 16);
}
__device__ __forceinline__ ushort_t cvt_rne(float v) {
    uint_t u = __float_as_uint(v);
    return (ushort_t)((u + 0x7FFFu + ((u >> 16) & 1u)) >> 16);
}
__device__ __forceinline__ float bf2f(ushort_t u) {
    return __uint_as_float((uint_t)u << 16);
}
// pa = packed (h<<16)|l for k=2i, pb for k=2i+1 -> hw/lw = bf16x2 hi/lo words
__device__ __forceinline__ void unpack2(uint_t pa, uint_t pb, uint_t& hw, uint_t& lw) {
    hw = __builtin_amdgcn_perm(pb, pa, 0x07060302u);  // [pa.h, pb.h]
    lw = __builtin_amdgcn_perm(pb, pa, 0x05040100u);  // [pa.l, pb.l]
}
// Weight-plane chunk swizzle: element (n,k) of a [N,K] k-major plane lives at
// n*K + (k&~31) | ((((k>>3)&3) ^ ((n>>1)&3))<<3) | (k&7).  16B chunks XOR'd
// within each 64B (32-elem) row-tile so a LINEAR global_load_lds copy yields
// bank-conflict-free ds_read_b128 fragment reads (2 lanes/bank-group = free).
__device__ __forceinline__ size_t swz(int n, int k, int K) {
    return (size_t)n * K +
           (size_t)((k & ~31) | ((((k >> 3) & 3) ^ ((n >> 1) & 3)) << 3) | (k & 7));
}
// 16B global -> LDS DMA (dest = wave-uniform base + lane*16)
__device__ __forceinline__ void gload16(const ushort_t* g, ushort_t* l) {
    __builtin_amdgcn_global_load_lds(
        (const __attribute__((address_space(1))) void*)g,
        (__attribute__((address_space(3))) void*)l, 16, 0, 0);
}

#define EPI_NONE 0
#define EPI_GELU 1
#define EPI_ADDS 3

// bgemm epilogue modes
#define BEP_P   0   // bf16 row-major out
#define BEP_PT  1   // bf16 row-major + col-major [N,M]
#define BEP_A1  2   // g1=gelu rm + gp=dgelu rm + g1T ct
#define BEP_DAT 3   // acc * gp(bf16) -> col-major only

// ---------------------------------------------------------------------------
// 3-pass split-bf16 GEMM (fp32-class). Phase C only.
// B planes (swizzled weights) staged via global_load_lds into unpadded LDS;
// A staged through registers into padded LDS (unpack / split on the fly).
// ---------------------------------------------------------------------------
template<int ACONCAT, int APACK, int EPI, int OPACK>
__global__ __launch_bounds__(256)
void mgemm_k(const float* A, const float* A2, const uint_t* __restrict__ AP,
             const ushort_t* __restrict__ BTh, const ushort_t* __restrict__ BTl,
             const float* __restrict__ bias, const ushort_t* __restrict__ Xr,
             float* C, uint_t* Cp,
             int M, int N, int K)
{
    __shared__ ushort_t Ah[128 * 40], Al[128 * 40];
    __shared__ ushort_t Bh[128 * 32], Bl[128 * 32];
    const int tid = threadIdx.x;
    const int m0 = blockIdx.x * 128, n0 = blockIdx.y * 128;
    const int lane = tid & 63, w = tid >> 6;
    const int wm = (w & 1) * 64, wn = (w >> 1) * 64;
    const int fr = lane & 15, fq = lane >> 4;
    const int sr = tid >> 1;
    const int sk = (tid & 1) * 16;

    f32x4 acc[4][4];
    #pragma unroll
    for (int i = 0; i < 4; i++)
        #pragma unroll
        for (int j = 0; j < 4; j++) acc[i][j] = (f32x4){0.f, 0.f, 0.f, 0.f};

    for (int k0 = 0; k0 < K; k0 += 32) {
        // ---- B: async DMA, linear LDS (source pre-swizzled) ----
        {
            const int r0w = w * 32;
            const size_t so = (size_t)(n0 + r0w + (lane >> 2)) * K + k0 + ((lane & 3) << 3);
            gload16(&BTh[so],                  &Bh[r0w * 32]);
            gload16(&BTh[so + (size_t)16 * K], &Bh[(r0w + 16) * 32]);
            gload16(&BTl[so],                  &Bl[r0w * 32]);
            gload16(&BTl[so + (size_t)16 * K], &Bl[(r0w + 16) * 32]);
        }
        // ---- A: register staging ----
        if (APACK) {
            const uint_t* ap = AP + (size_t)(m0 + sr) * K + k0 + sk;
            uint4 p0 = *(const uint4*)(ap);
            uint4 p1 = *(const uint4*)(ap + 4);
            uint4 p2 = *(const uint4*)(ap + 8);
            uint4 p3 = *(const uint4*)(ap + 12);
            uint4 h0, h1, l0, l1;
            unpack2(p0.x, p0.y, h0.x, l0.x); unpack2(p0.z, p0.w, h0.y, l0.y);
            unpack2(p1.x, p1.y, h0.z, l0.z); unpack2(p1.z, p1.w, h0.w, l0.w);
            unpack2(p2.x, p2.y, h1.x, l1.x); unpack2(p2.z, p2.w, h1.y, l1.y);
            unpack2(p3.x, p3.y, h1.z, l1.z); unpack2(p3.z, p3.w, h1.w, l1.w);
            *(uint4*)&Ah[sr * 40 + sk]     = h0;
            *(uint4*)&Ah[sr * 40 + sk + 8] = h1;
            *(uint4*)&Al[sr * 40 + sk]     = l0;
            *(uint4*)&Al[sr * 40 + sk + 8] = l1;
        } else {
            #pragma unroll
            for (int g = 0; g < 2; g++) {
                uint4 qh, qa;
                uint_t ph[4], pl[4];
                #pragma unroll
                for (int c = 0; c < 2; c++) {
                    const int ak = k0 + sk + g * 8 + c * 4;
                    const float* ap;
                    if (ACONCAT) ap = (ak < 256) ? (A + (size_t)(m0 + sr) * 256 + ak)
                                                 : (A2 + (size_t)(m0 + sr) * 256 + (ak - 256));
                    else         ap = A + (size_t)(m0 + sr) * K + ak;
                    float4 v = *(const float4*)ap;
                    ushort_t h0,h1,h2,h3,l0,l1,l2,l3;
                    splitf(v.x,h0,l0); splitf(v.y,h1,l1); splitf(v.z,h2,l2); splitf(v.w,h3,l3);
                    ph[c*2]   = (uint_t)h0 | ((uint_t)h1 << 16);
                    ph[c*2+1] = (uint_t)h2 | ((uint_t)h3 << 16);
                    pl[c*2]   = (uint_t)l0 | ((uint_t)l1 << 16);
                    pl[c*2+1] = (uint_t)l2 | ((uint_t)l3 << 16);
                }
                qh.x = ph[0]; qh.y = ph[1]; qh.z = ph[2]; qh.w = ph[3];
                qa.x = pl[0]; qa.y = pl[1]; qa.z = pl[2]; qa.w = pl[3];
                *(uint4*)&Ah[sr * 40 + sk + g * 8] = qh;
                *(uint4*)&Al[sr * 40 + sk + g * 8] = qa;
            }
        }
        __syncthreads();

        frag8 afh[4], afl[4], bfh[4], bfl[4];
        #pragma unroll
        for (int i = 0; i < 4; i++) {
            const int ar = wm + i * 16 + fr;
            afh[i] = *(frag8*)&Ah[ar * 40 + fq * 8];
            afl[i] = *(frag8*)&Al[ar * 40 + fq * 8];
        }
        #pragma unroll
        for (int j = 0; j < 4; j++) {
            const int br = wn + j * 16 + fr;
            const int bs = br * 32 + ((fq ^ ((br >> 1) & 3)) << 3);
            bfh[j] = *(frag8*)&Bh[bs];
            bfl[j] = *(frag8*)&Bl[bs];
        }
        #pragma unroll
        for (int i = 0; i < 4; i++)
            #pragma unroll
            for (int j = 0; j < 4; j++) {
                acc[i][j] = __builtin_amdgcn_mfma_f32_16x16x32_bf16(afh[i], bfh[j], acc[i][j], 0, 0, 0);
                acc[i][j] = __builtin_amdgcn_mfma_f32_16x16x32_bf16(afh[i], bfl[j], acc[i][j], 0, 0, 0);
                acc[i][j] = __builtin_amdgcn_mfma_f32_16x16x32_bf16(afl[i], bfh[j], acc[i][j], 0, 0, 0);
            }
        __syncthreads();
    }

    float bv[4] = {0.f, 0.f, 0.f, 0.f};
    if (bias != nullptr)
        #pragma unroll
        for (int j = 0; j < 4; j++) bv[j] = bias[n0 + wn + j * 16 + fr];
    #pragma unroll
    for (int i = 0; i < 4; i++)
        #pragma unroll
        for (int j = 0; j < 4; j++) {
            const int col = n0 + wn + j * 16 + fr;
            #pragma unroll
            for (int r = 0; r < 4; r++) {
                const int row = m0 + wm + i * 16 + fq * 4 + r;
                const size_t off = (size_t)row * N + col;
                float c = acc[i][j][r] + bv[j];
                if (EPI == EPI_GELU)      c = gelu_f(c);
                else if (EPI == EPI_ADDS) c = c + 0.1f * bf2f(Xr[off]);
                if (OPACK) {
                    ushort_t h, l;
                    splitf(c, h, l);
                    Cp[off] = ((uint_t)h << 16) | (uint_t)l;
                } else {
                    C[off] = c;
                }
            }
        }
}

// ---------------------------------------------------------------------------
// 1-pass bf16 GEMM (Phase A). B plane (swizzled weights) via global_load_lds;
// A through registers into padded LDS. Optional fused column-sum (dbsum):
// for de (BEP_PT -> db2) and da (BEP_DAT -> db1) epilogues, accumulates the
// fp32 per-column sums and atomically adds them — replaces colsumT passes.
// ---------------------------------------------------------------------------
template<int ACONCAT, int BEP>
__global__ __launch_bounds__(256)
void bgemm_k(const void* Av, const float* A2f, const ushort_t* __restrict__ BTh,
             const float* __restrict__ bias, const ushort_t* __restrict__ GpIn,
             ushort_t* Crm, ushort_t* Cct, ushort_t* GpOut, float* dbsum,
             int M, int N, int K)
{
    __shared__ ushort_t Ah[128 * 40];
    __shared__ ushort_t Bh[128 * 32];
    const int tid = threadIdx.x;
    const int m0 = blockIdx.x * 128, n0 = blockIdx.y * 128;
    const int lane = tid & 63, w = tid >> 6;
    const int wm = (w & 1) * 64, wn = (w >> 1) * 64;
    const int fr = lane & 15, fq = lane >> 4;
    const int sr = tid >> 1;
    const int sk = (tid & 1) * 16;

    f32x4 acc[4][4];
    #pragma unroll
    for (int i = 0; i < 4; i++)
        #pragma unroll
        for (int j = 0; j < 4; j++) acc[i][j] = (f32x4){0.f, 0.f, 0.f, 0.f};

    for (int k0 = 0; k0 < K; k0 += 32) {
        // ---- B: async DMA ----
        {
            const int r0w = w * 32;
            const size_t so = (size_t)(n0 + r0w + (lane >> 2)) * K + k0 + ((lane & 3) << 3);
            gload16(&BTh[so],                  &Bh[r0w * 32]);
            gload16(&BTh[so + (size_t)16 * K], &Bh[(r0w + 16) * 32]);
        }
        // ---- A ----
        if (ACONCAT) {
            const float* A = (const float*)Av;
            #pragma unroll
            for (int g = 0; g < 2; g++) {
                uint_t ph[4];
                #pragma unroll
                for (int c = 0; c < 2; c++) {
                    const int ak = k0 + sk + g * 8 + c * 4;
                    const float* ap = (ak < 256) ? (A + (size_t)(m0 + sr) * 256 + ak)
                                                 : (A2f + (size_t)(m0 + sr) * 256 + (ak - 256));
                    float4 v = *(const float4*)ap;
                    ph[c*2]   = (uint_t)cvt_rne(v.x) | ((uint_t)cvt_rne(v.y) << 16);
                    ph[c*2+1] = (uint_t)cvt_rne(v.z) | ((uint_t)cvt_rne(v.w) << 16);
                }
                uint4 q; q.x = ph[0]; q.y = ph[1]; q.z = ph[2]; q.w = ph[3];
                *(uint4*)&Ah[sr * 40 + sk + g * 8] = q;
            }
        } else {
            const ushort_t* A = (const ushort_t*)Av;
            const size_t ao = (size_t)(m0 + sr) * K + k0 + sk;
            *(uint4*)&Ah[sr * 40 + sk]     = *(const uint4*)&A[ao];
            *(uint4*)&Ah[sr * 40 + sk + 8] = *(const uint4*)&A[ao + 8];
        }
        __syncthreads();

        frag8 af[4], bf[4];
        #pragma unroll
        for (int i = 0; i < 4; i++) af[i] = *(frag8*)&Ah[(wm + i * 16 + fr) * 40 + fq * 8];
        #pragma unroll
        for (int j = 0; j < 4; j++) {
            const int br = wn + j * 16 + fr;
            bf[j] = *(frag8*)&Bh[br * 32 + ((fq ^ ((br >> 1) & 3)) << 3)];
        }
        #pragma unroll
        for (int i = 0; i < 4; i++)
            #pragma unroll
            for (int j = 0; j < 4; j++)
                acc[i][j] = __builtin_amdgcn_mfma_f32_16x16x32_bf16(af[i], bf[j], acc[i][j], 0, 0, 0);
        __syncthreads();
    }

    float bv[4] = {0.f, 0.f, 0.f, 0.f};
    if (bias != nullptr)
        #pragma unroll
        for (int j = 0; j < 4; j++) bv[j] = bias[n0 + wn + j * 16 + fr];
    float cs[4] = {0.f, 0.f, 0.f, 0.f};
    #pragma unroll
    for (int i = 0; i < 4; i++)
        #pragma unroll
        for (int j = 0; j < 4; j++) {
            const int col = n0 + wn + j * 16 + fr;
            const int rowb = m0 + wm + i * 16 + fq * 4;
            float v[4];
            #pragma unroll
            for (int r = 0; r < 4; r++) v[r] = acc[i][j][r] + bv[j];
            if (BEP == BEP_A1) {
                ushort_t gc[4];
                #pragma unroll
                for (int r = 0; r < 4; r++) {
                    float g, d;
                    gelu_pair(v[r], g, d);
                    gc[r] = cvt_rne(g);
                    Crm[(size_t)(rowb + r) * N + col] = gc[r];
                    GpOut[(size_t)(rowb + r) * N + col] = cvt_rne(d);
                }
                uint_t p0 = (uint_t)gc[0] | ((uint_t)gc[1] << 16);
                uint_t p1 = (uint_t)gc[2] | ((uint_t)gc[3] << 16);
                *(uint2*)&Cct[(size_t)col * M + rowb] = (uint2){p0, p1};
            } else if (BEP == BEP_DAT) {
                ushort_t dc[4];
                #pragma unroll
                for (int r = 0; r < 4; r++) {
                    float pr = v[r] * bf2f(GpIn[(size_t)(rowb + r) * N + col]);
                    dc[r] = cvt_rne(pr);
                    cs[j] += pr;
                }
                uint_t p0 = (uint_t)dc[0] | ((uint_t)dc[1] << 16);
                uint_t p1 = (uint_t)dc[2] | ((uint_t)dc[3] << 16);
                *(uint2*)&Cct[(size_t)col * M + rowb] = (uint2){p0, p1};
            } else {
                ushort_t cc[4];
                #pragma unroll
                for (int r = 0; r < 4; r++) {
                    cc[r] = cvt_rne(v[r]);
                    Crm[(size_t)(rowb + r) * N + col] = cc[r];
                }
                cs[j] += v[0] + v[1] + v[2] + v[3];
                if (BEP == BEP_PT) {
                    uint_t p0 = (uint_t)cc[0] | ((uint_t)cc[1] << 16);
                    uint_t p1 = (uint_t)cc[2] | ((uint_t)cc[3] << 16);
                    *(uint2*)&Cct[(size_t)col * M + rowb] = (uint2){p0, p1};
                }
            }
        }
    if (dbsum != nullptr) {
        #pragma unroll
        for (int j = 0; j < 4; j++) {
            float s = cs[j];
            s += __shfl_xor(s, 16);
            s += __shfl_xor(s, 32);
            if (fq == 0) atomicAdd(&dbsum[n0 + wn + j * 16 + fr], s);
        }
    }
}

// ---------------------------------------------------------------------------
// Weight-grad: C[M,N] += AT[M,:]·BT[N,:] over split-K chunk. Both k-major bf16.
// ---------------------------------------------------------------------------
__global__ __launch_bounds__(256)
void wgrad_k(const ushort_t* __restrict__ AT, const ushort_t* __restrict__ BTt,
             float* C, int M, int N, int KA, int kofsA, int KB, int kofsB, int KC)
{
    __shared__ ushort_t Ah[128 * 40];
    __shared__ ushort_t Bh[128 * 40];
    const int tid = threadIdx.x;
    const int m0 = blockIdx.x * 128, n0 = blockIdx.y * 128;
    const int kbA = kofsA + blockIdx.z * KC;
    const int kbB = kofsB + blockIdx.z * KC;
    const int lane = tid & 63, w = tid >> 6;
    const int wm = (w & 1) * 64, wn = (w >> 1) * 64;
    const int fr = lane & 15, fq = lane >> 4;
    const int sr = tid >> 1;
    const int sk = (tid & 1) * 16;

    f32x4 acc[4][4];
    #pragma unroll
    for (int i = 0; i < 4; i++)
        #pragma unroll
        for (int j = 0; j < 4; j++) acc[i][j] = (f32x4){0.f, 0.f, 0.f, 0.f};

    for (int k0 = 0; k0 < KC; k0 += 32) {
        const size_t ao = (size_t)(m0 + sr) * KA + kbA + k0 + sk;
        *(uint4*)&Ah[sr * 40 + sk]     = *(const uint4*)&AT[ao];
        *(uint4*)&Ah[sr * 40 + sk + 8] = *(const uint4*)&AT[ao + 8];
        const size_t bo = (size_t)(n0 + sr) * KB + kbB + k0 + sk;
        *(uint4*)&Bh[sr * 40 + sk]     = *(const uint4*)&BTt[bo];
        *(uint4*)&Bh[sr * 40 + sk + 8] = *(const uint4*)&BTt[bo + 8];
        __syncthreads();

        frag8 af[4], bf[4];
        #pragma unroll
        for (int i = 0; i < 4; i++) af[i] = *(frag8*)&Ah[(wm + i * 16 + fr) * 40 + fq * 8];
        #pragma unroll
        for (int j = 0; j < 4; j++) bf[j] = *(frag8*)&Bh[(wn + j * 16 + fr) * 40 + fq * 8];
        #pragma unroll
        for (int i = 0; i < 4; i++)
            #pragma unroll
            for (int j = 0; j < 4; j++)
                acc[i][j] = __builtin_amdgcn_mfma_f32_16x16x32_bf16(af[i], bf[j], acc[i][j], 0, 0, 0);
        __syncthreads();
    }
    #pragma unroll
    for (int i = 0; i < 4; i++)
        #pragma unroll
        for (int j = 0; j < 4; j++) {
            const int col = n0 + wn + j * 16 + fr;
            #pragma unroll
            for (int r = 0; r < 4; r++) {
                const int row = m0 + wm + i * 16 + fq * 4 + r;
                atomicAdd(&C[(size_t)row * N + col], acc[i][j][r]);
            }
        }
}

// LayerNorm fwd + dL/dr0, bf16 in/out (dr0 may alias r0)
__global__ __launch_bounds__(256)
void ln_bf_k(const ushort_t* r0, const ushort_t* __restrict__ phi,
             const float* __restrict__ gamma, const float* __restrict__ beta,
             ushort_t* recon, ushort_t* dr0)
{
    const int lane = threadIdx.x & 63;
    const int wv = threadIdx.x >> 6;
    const int row = blockIdx.x * 4 + wv;
    const size_t base = (size_t)row * U_N + (lane << 2);

    uint2 xu = *(const uint2*)(r0 + base);
    uint2 pu = *(const uint2*)(phi + base);
    float xs[4] = { bf2f((ushort_t)(xu.x & 0xFFFF)), bf2f((ushort_t)(xu.x >> 16)),
                    bf2f((ushort_t)(xu.y & 0xFFFF)), bf2f((ushort_t)(xu.y >> 16)) };
    float ps[4] = { bf2f((ushort_t)(pu.x & 0xFFFF)), bf2f((ushort_t)(pu.x >> 16)),
                    bf2f((ushort_t)(pu.y & 0xFFFF)), bf2f((ushort_t)(pu.y >> 16)) };
    float s = xs[0] + xs[1] + xs[2] + xs[3];
    float sq = xs[0]*xs[0] + xs[1]*xs[1] + xs[2]*xs[2] + xs[3]*xs[3];
    #pragma unroll
    for (int o = 32; o > 0; o >>= 1) { s += __shfl_xor(s, o); sq += __shfl_xor(sq, o); }
    const float m   = s * (1.0f / U_N);
    const float var = sq * (1.0f / U_N) - m * m;
    const float inv = rsqrtf(var + EPS_C);

    float4 gv = *(const float4*)(gamma + (lane << 2));
    float4 bvv = *(const float4*)(beta + (lane << 2));
    float gs[4] = {gv.x, gv.y, gv.z, gv.w};
    float bs[4] = {bvv.x, bvv.y, bvv.z, bvv.w};
    float rh[4], dh[4], rc[4];
    float s1 = 0.f, s2 = 0.f;
    const float gscale = 2.0f / ((float)B_N * (float)U_N);
    #pragma unroll
    for (int j = 0; j < 4; j++) {
        rh[j] = (xs[j] - m) * inv;
        rc[j] = rh[j] * gs[j] + bs[j];
        float g2 = gscale * (rc[j] - ps[j]);
        dh[j] = g2 * gs[j];
        s1 += dh[j];
        s2 += dh[j] * rh[j];
    }
    #pragma unroll
    for (int o = 32; o > 0; o >>= 1) { s1 += __shfl_xor(s1, o); s2 += __shfl_xor(s2, o); }
    const float mu1 = s1 * (1.0f / U_N);
    const float mu2 = s2 * (1.0f / U_N);
    ushort_t oc[4], dc[4];
    #pragma unroll
    for (int j = 0; j < 4; j++) {
        oc[j] = cvt_rne(rc[j]);
        dc[j] = cvt_rne(inv * (dh[j] - mu1 - rh[j] * mu2));
    }
    *(uint2*)(recon + base) = (uint2){ (uint_t)oc[0] | ((uint_t)oc[1] << 16),
                                       (uint_t)oc[2] | ((uint_t)oc[3] << 16) };
    *(uint2*)(dr0 + base)   = (uint2){ (uint_t)dc[0] | ((uint_t)dc[1] << 16),
                                       (uint_t)dc[2] | ((uint_t)dc[3] << 16) };
}

// transpose + split: W [R,C] fp32 -> Th (+Tl if HASL) [C,R], chunk-swizzled
template<int HASL>
__global__ __launch_bounds__(256)
void tsplit_k(const float* __restrict__ W, ushort_t* __restrict__ Th,
              ushort_t* __restrict__ Tl, int R, int C)
{
    __shared__ float t[64][65];
    const int tid = threadIdx.x;
    const int R0 = blockIdx.x * 64, C0 = blockIdx.y * 64;
    const int c = tid & 63, rb = (tid >> 6) * 16;
    for (int i = 0; i < 16; i++)
        t[rb + i][c] = W[(size_t)(R0 + rb + i) * C + C0 + c];
    __syncthreads();
    const int orr = tid & 63, ob = (tid >> 6) * 16;
    for (int i = 0; i < 16; i++) {
        const int oc = ob + i;
        ushort_t h, l;
        splitf(t[orr][oc], h, l);
        const size_t d = swz(C0 + oc, R0 + orr, R);
        Th[d] = h;
        if (HASL) Tl[d] = l;
    }
}

// transpose + SGD update + split (hi+lo), chunk-swizzled
__global__ __launch_bounds__(256)
void tupd_k(const float* __restrict__ W, const float* __restrict__ dW,
            ushort_t* __restrict__ Th, ushort_t* __restrict__ Tl, int R, int C)
{
    __shared__ float t[64][65];
    const int tid = threadIdx.x;
    const int R0 = blockIdx.x * 64, C0 = blockIdx.y * 64;
    const int c = tid & 63, rb = (tid >> 6) * 16;
    for (int i = 0; i < 16; i++) {
        const size_t o = (size_t)(R0 + rb + i) * C + C0 + c;
        t[rb + i][c] = W[o] - LR_C * dW[o];
    }
    __syncthreads();
    const int orr = tid & 63, ob = (tid >> 6) * 16;
    for (int i = 0; i < 16; i++) {
        const int oc = ob + i;
        ushort_t h, l;
        splitf(t[orr][oc], h, l);
        const size_t d = swz(C0 + oc, R0 + orr, R);
        Th[d] = h;
        Tl[d] = l;
    }
}

// elementwise hi-plane convert, chunk-swizzled. Row length fixed at 256.
__global__ __launch_bounds__(256)
void scvt_k(const float* __restrict__ W, ushort_t* __restrict__ Th, int n4)
{
    const int i = blockIdx.x * 256 + threadIdx.x;
    if (i >= n4) return;
    float4 v = *(const float4*)(W + (size_t)i * 4);
    const int f = i * 4;
    const int row = f >> 8, col = f & 255;
    uint2 ph;
    ph.x = (uint_t)cvt_rne(v.x) | ((uint_t)cvt_rne(v.y) << 16);
    ph.y = (uint_t)cvt_rne(v.z) | ((uint_t)cvt_rne(v.w) << 16);
    *(uint2*)&Th[swz(row, col, 256)] = ph;
}

// Wc = W2 @ Wg (fp32): W2 [1024,256], Wg [256,256] -> Wc [1024,256]
__global__ __launch_bounds__(256)
void wcmul_k(const float* __restrict__ W2, const float* __restrict__ Wg,
             float* __restrict__ Wc)
{
    const int i = blockIdx.x;
    const int j = threadIdx.x;
    float s = 0.f;
    for (int k = 0; k < 256; k++)
        s = fmaf(W2[i * 256 + k], Wg[k * 256 + j], s);
    Wc[i * 256 + j] = s;
}
// bc = b2 @ Wg + g_bias
__global__ __launch_bounds__(256)
void bcmul_k(const float* __restrict__ b2, const float* __restrict__ Wg,
             const float* __restrict__ gb, float* __restrict__ bc)
{
    const int j = threadIdx.x;
    float s = gb[j];
    for (int k = 0; k < 256; k++)
        s = fmaf(b2[k], Wg[k * 256 + j], s);
    bc[j] = s;
}

__global__ __launch_bounds__(256)
void bupd_k(const float* __restrict__ b1, const float* __restrict__ db1,
            const float* __restrict__ b2, const float* __restrict__ db2,
            float* __restrict__ b1u, float* __restrict__ b2u)
{
    const int i = blockIdx.x * 256 + threadIdx.x;
    if (i < H_N) b1u[i] = b1[i] - LR_C * db1[i];
    else if (i < H_N + U_N) b2u[i - H_N] = b2[i - H_N] - LR_C * db2[i - H_N];
}

extern "C" void kernel_launch(void* const* d_in, const int* in_sizes, int n_in,
                              void* d_out, int out_size, void* d_ws, size_t ws_size,
                              hipStream_t stream)
{
    const float* x      = (const float*)d_in[0];
    const float* h_prev = (const float*)d_in[1];
    const float* W_phi  = (const float*)d_in[2];
    const float* b_phi  = (const float*)d_in[3];
    const float* W_psi  = (const float*)d_in[4];
    const float* b_psi  = (const float*)d_in[5];
    const float* W1     = (const float*)d_in[6];
    const float* b1     = (const float*)d_in[7];
    const float* W2     = (const float*)d_in[8];
    const float* b2     = (const float*)d_in[9];
    const float* W_g    = (const float*)d_in[10];
    const float* g_bias = (const float*)d_in[11];
    const float* gamma  = (const float*)d_in[12];
    const float* beta   = (const float*)d_in[13];
    const float* W_h    = (const float*)d_in[14];
    const float* h_bias = (const float*)d_in[15];
    float* out = (float*)d_out;

    const size_t BU = (size_t)B_N * U_N;
    const size_t UH = (size_t)U_N * H_N;

    // ---- fixed allocations ----
    float* ws  = (float*)d_ws;
    float* dW1 = ws;                      // [U,H]
    float* db1 = dW1 + UH;                // [H]
    float* dW2 = db1 + H_N;               // [H,U]
    float* db2 = dW2 + UH;                // [U]
    float* b1u = db2 + U_N;
    float* b2u = b1u + H_N;
    float* bc  = b2u + U_N;               // [U] fused r0 bias
    float* Wc  = bc + U_N;                // [H,U] fp32 = W2@Wg
    ushort_t* us = (ushort_t*)(((uintptr_t)(Wc + UH) + 15) & ~(uintptr_t)15);
    // weight planes (all chunk-swizzled)
    ushort_t* WphiT_h = us;                   // [U,512]
    ushort_t* WpsiT_h = WphiT_h + 131072;     ushort_t* WpsiT_l = WpsiT_h + 131072;
    ushort_t* WcT_h   = WpsiT_l + 131072;     // [U,H] (was W1T slot; Wc^T)
    ushort_t* W1T_h   = WcT_h + 262144;       // [H,U]
    ushort_t* W2s_h   = W1T_h + 262144;       // W2 row-major [H,U]
    ushort_t* Wgs_h   = W2s_h + 262144;       // Wg row-major
    ushort_t* W1uT_h  = Wgs_h + 65536;        ushort_t* W1uT_l = W1uT_h + 262144;
    ushort_t* W2uT_h  = W1uT_l + 262144;      ushort_t* W2uT_l = W2uT_h + 262144;
    ushort_t* WhT_h   = W2uT_l + 262144;      ushort_t* WhT_l  = WhT_h + 65536;
    // persistent bf16 activations
    ushort_t* phi_bf  = WhT_l + 65536;        // [B,U]
    ushort_t* phiT_bf = phi_bf + BU;          // [U,B]
    ushort_t* recon_bf= phiT_bf + BU;         // [B,U]
    ushort_t* chunk0  = recon_bf + BU;        // chunk region start
    const size_t P_bytes = (size_t)((char*)chunk0 - (char*)d_ws);

    // ---- chunk sizing ----
    int GA = 2;
    while (GA < 256 && P_bytes + (size_t)(B_N / GA) * 10240 + (1 << 20) > ws_size) GA *= 2;
    size_t region = (size_t)(B_N / GA) * 10240;
    int GC = 1;
    while (GC < 256) {
        size_t cC = (size_t)(B_N / GC) * 6144;
        size_t r = cC > region ? cC : region;
        if (P_bytes + r + (1 << 20) <= ws_size) { region = r; break; }
        GC *= 2;
    }
    const int BcA = B_N / GA;
    const int BcC = B_N / GC;
    const int KC = (BcA >= 8192) ? 512 : ((BcA >= 1024) ? BcA / 16 : BcA);
    const int Z  = BcA / KC;

    // Phase A chunk buffers (bf16)
    ushort_t* g1  = chunk0;                       // [BcA,H]
    ushort_t* gp  = g1  + (size_t)BcA * H_N;      // [BcA,H]
    ushort_t* g1T = gp  + (size_t)BcA * H_N;      // [H,BcA]
    ushort_t* daT = g1T + (size_t)BcA * H_N;      // [H,BcA]
    ushort_t* e_b = daT + (size_t)BcA * H_N;      // [BcA,U]  (unused; layout kept)
    ushort_t* r0b = e_b + (size_t)BcA * U_N;      // [BcA,U]  (r0 -> dr0)
    ushort_t* deb = r0b + (size_t)BcA * U_N;      // [BcA,U]
    ushort_t* deT = deb + (size_t)BcA * U_N;      // [U,BcA]
    // Phase C chunk buffers (packed hi|lo words, overlay same region)
    uint_t* psi_p  = (uint_t*)chunk0;             // [BcC,U]
    uint_t* h2_p   = psi_p + (size_t)BcC * U_N;   // [BcC,H]
    uint_t* feat_p = h2_p  + (size_t)BcC * H_N;   // [BcC,U]

    hipMemsetAsync(dW1, 0, (2 * UH + H_N + U_N) * sizeof(float), stream);

    dim3 blk(256);
    // weight prep (planes stored chunk-swizzled)
    tsplit_k<0><<<dim3(8, 4),  blk, 0, stream>>>(W_phi, WphiT_h, nullptr, 512, 256);
    tsplit_k<1><<<dim3(8, 4),  blk, 0, stream>>>(W_psi, WpsiT_h, WpsiT_l, 512, 256);
    tsplit_k<0><<<dim3(4, 16), blk, 0, stream>>>(W1, W1T_h, nullptr, 256, 1024);
    tsplit_k<1><<<dim3(4, 4),  blk, 0, stream>>>(W_h, WhT_h, WhT_l, 256, 256);
    scvt_k<<<dim3(256), blk, 0, stream>>>(W2, W2s_h, 65536);
    scvt_k<<<dim3(64),  blk, 0, stream>>>(W_g, Wgs_h, 16384);
    // Wc = W2@Wg, bc = b2@Wg + g_bias (folds the e-GEMM away)
    wcmul_k<<<dim3(1024), blk, 0, stream>>>(W2, W_g, Wc);
    bcmul_k<<<dim3(1), blk, 0, stream>>>(b2, W_g, g_bias, bc);
    tsplit_k<0><<<dim3(16, 4), blk, 0, stream>>>(Wc, WcT_h, nullptr, 1024, 256);

    // phi = [x|h_prev] @ W_phi + b_phi  (1-pass, bf16 out rm + T)
    bgemm_k<1, BEP_PT><<<dim3(B_N / 128, 2), blk, 0, stream>>>(
        x, h_prev, WphiT_h, b_phi, nullptr, phi_bf, phiT_bf, nullptr, nullptr,
        B_N, U_N, 512);

    // ---- Phase A: inner fwd+bwd, 1-pass bf16, chunked ----
    for (int c = 0; c < GA; c++) {
        const size_t off = (size_t)c * BcA;
        const ushort_t* phic = phi_bf + off * U_N;
        // a1 = phi@W1+b1 -> g1(gelu) rm, gp(dgelu) rm, g1T ct
        bgemm_k<0, BEP_A1><<<dim3(BcA / 128, 8), blk, 0, stream>>>(
            phic, nullptr, W1T_h, b1, nullptr, g1, g1T, gp, nullptr, BcA, H_N, U_N);
        // r0 = g1@(W2@Wg) + bc   (e-GEMM eliminated)
        bgemm_k<0, BEP_P><<<dim3(BcA / 128, 2), blk, 0, stream>>>(
            g1, nullptr, WcT_h, bc, nullptr, r0b, nullptr, nullptr, nullptr,
            BcA, U_N, H_N);
        // recon, dr0 (in-place over r0b)
        ln_bf_k<<<dim3(BcA / 4), blk, 0, stream>>>(r0b, phic, gamma, beta,
                                                   recon_bf + off * U_N, r0b);
        // de = dr0@Wg^T -> rm + T ; db2 += colsum (fused)
        bgemm_k<0, BEP_PT><<<dim3(BcA / 128, 2), blk, 0, stream>>>(
            r0b, nullptr, Wgs_h, nullptr, nullptr, deb, deT, nullptr, db2,
            BcA, U_N, U_N);
        // da = (de@W2^T)*gp -> daT ; db1 += colsum (fused)
        bgemm_k<0, BEP_DAT><<<dim3(BcA / 128, 8), blk, 0, stream>>>(
            deb, nullptr, W2s_h, nullptr, gp, nullptr, daT, nullptr, db1,
            BcA, H_N, U_N);
        // dW2 += g1T·deT
        wgrad_k<<<dim3(8, 2, Z), blk, 0, stream>>>(g1T, deT, dW2, H_N, U_N,
                                                   BcA, 0, BcA, 0, KC);
        // dW1 += phiT·daT
        wgrad_k<<<dim3(2, 8, Z), blk, 0, stream>>>(phiT_bf, daT, dW1, U_N, H_N,
                                                   B_N, (int)off, BcA, 0, KC);
    }

    // ---- Phase B: updated params ----
    bupd_k<<<dim3(5), blk, 0, stream>>>(b1, db1, b2, db2, b1u, b2u);
    tupd_k<<<dim3(4, 16), blk, 0, stream>>>(W1, dW1, W1uT_h, W1uT_l, 256, 1024);
    tupd_k<<<dim3(16, 4), blk, 0, stream>>>(W2, dW2, W2uT_h, W2uT_l, 1024, 256);

    // ---- Phase C: 3-pass forward, packed hi|lo threaded between GEMMs ----
    for (int c = 0; c < GC; c++) {
        const size_t off = (size_t)c * BcC;
        // psi = [x|h] @ W_psi + b_psi -> packed
        mgemm_k<1, 0, EPI_NONE, 1><<<dim3(BcC / 128, 2), blk, 0, stream>>>(
            x + off * 256, h_prev + off * U_N, nullptr,
            WpsiT_h, WpsiT_l, b_psi, nullptr,
            nullptr, psi_p, BcC, U_N, 512);
        // h2 = gelu(psi @ W1u + b1u) -> packed
        mgemm_k<0, 1, EPI_GELU, 1><<<dim3(BcC / 128, 8), blk, 0, stream>>>(
            nullptr, nullptr, psi_p,
            W1uT_h, W1uT_l, b1u, nullptr,
            nullptr, h2_p, BcC, H_N, U_N);
        // feat = h2 @ W2u + b2u + 0.1*recon -> packed
        mgemm_k<0, 1, EPI_ADDS, 1><<<dim3(BcC / 128, 2), blk, 0, stream>>>(
            nullptr, nullptr, h2_p,
            W2uT_h, W2uT_l, b2u, recon_bf + off * U_N,
            nullptr, feat_p, BcC, U_N, H_N);
        // out = feat @ W_h + h_bias (fp32)
        mgemm_k<0, 1, EPI_NONE, 0><<<dim3(BcC / 128, 2), blk, 0, stream>>>(
            nullptr, nullptr, feat_p,
            WhT_h, WhT_l, h_bias, nullptr,
            out + off * U_N, nullptr, BcC, U_N, U_N);
    }
}